// Round 13
// baseline (202.346 us; speedup 1.0000x reference)
//
#include <hip/hip_runtime.h>
#include <hip/hip_bf16.h>
#include <stdint.h>

#define NH 12
#define DH 64
#define SEQ 4096
#define DM 768
#define NEGV -1e9f
#define LOG2E 1.4426950408889634f
#define QSCALE 0.1803368801111601f  // 0.125 * log2(e)

using bf16x8 = __attribute__((ext_vector_type(8))) short;
using f32x4  = __attribute__((ext_vector_type(4))) float;

static __device__ __forceinline__ short f2bf(float f) {
  unsigned u = __builtin_bit_cast(unsigned, f);
  u += 0x7fffu + ((u >> 16) & 1u);
  return (short)(u >> 16);
}

static __device__ __forceinline__ unsigned pack2bf(float lo, float hi) {
  unsigned a = __builtin_bit_cast(unsigned, lo);
  a += 0x7fffu + ((a >> 16) & 1u);
  unsigned b = __builtin_bit_cast(unsigned, hi);
  b += 0x7fffu + ((b >> 16) & 1u);
  return (a >> 16) | (b & 0xffff0000u);
}

static __device__ __forceinline__ void gload16(const void* g, void* l) {
  __builtin_amdgcn_global_load_lds(
      (const __attribute__((address_space(1))) unsigned*)g,
      (__attribute__((address_space(3))) unsigned*)l, 16, 0, 0);
}

static __device__ __forceinline__ f32x4 mfma16(bf16x8 a, bf16x8 b, f32x4 c) {
  return __builtin_amdgcn_mfma_f32_16x16x32_bf16(a, b, c, 0, 0, 0);
}

#define SBAR() __builtin_amdgcn_sched_barrier(0)
#define WAIT8() asm volatile("s_waitcnt vmcnt(8)" ::: "memory")
#define WAIT4() asm volatile("s_waitcnt vmcnt(4)" ::: "memory")
#define WAIT0() asm volatile("s_waitcnt vmcnt(0)" ::: "memory")
#define LKWAIT() asm volatile("s_waitcnt lgkmcnt(0)" ::: "memory")
#define HBAR() __builtin_amdgcn_s_barrier()

// ---------------- conversion kernels ----------------
__global__ __launch_bounds__(256) void cvt_x(const float* __restrict__ X,
                                             short* __restrict__ Xb, int n4) {
  int i = blockIdx.x * 256 + threadIdx.x;
  if (i >= n4) return;
  float4 v = ((const float4*)X)[i];
  short4 o; o.x = f2bf(v.x); o.y = f2bf(v.y); o.z = f2bf(v.z); o.w = f2bf(v.w);
  ((short4*)Xb)[i] = o;
}

__global__ __launch_bounds__(256) void cvt_w(
    const float* __restrict__ Wq, const float* __restrict__ Wk,
    const float* __restrict__ Wv, const float* __restrict__ Wo,
    short* __restrict__ Wqkv, short* __restrict__ Wob) {
  int i = blockIdx.x * 256 + threadIdx.x;  // unit = 4 elems
  const int n1 = 2304 * 768 / 4;
  if (i < n1) {
    int e = i * 4;
    int row = e / 768;
    const float* src;
    float sc = 1.0f;
    if (row < 768)       { src = Wq + e; sc = QSCALE; }
    else if (row < 1536) { src = Wk + e - 768 * 768; }
    else                 { src = Wv + e - 1536 * 768; }
    float4 v = *(const float4*)src;
    short4 o; o.x = f2bf(v.x * sc); o.y = f2bf(v.y * sc);
    o.z = f2bf(v.z * sc); o.w = f2bf(v.w * sc);
    ((short4*)Wqkv)[i] = o;
  } else {
    int j = i - n1;
    if (j >= 768 * 768 / 4) return;
    float4 v = ((const float4*)Wo)[j];
    short4 o; o.x = f2bf(v.x); o.y = f2bf(v.y); o.z = f2bf(v.z); o.w = f2bf(v.w);
    ((short4*)Wob)[j] = o;
  }
}

// ======= pipelined 128x128xBK32 GEMM core (4-buffer, depth-3, counted vmcnt) =======
// (R6 version — measured best)
#define GEMM_PIPELINE(SM, AG, BG, ACC, LANE, WR, WC)                           \
  {                                                                            \
    const int l15 = (LANE) & 15, gw = (LANE) >> 4;                             \
    const int s_ = (l15 >> 1) & 3;                                             \
    const int fcol = ((gw ^ s_) << 3);                                         \
    const int NT = 24; /* 768/32 */                                            \
    auto stage = [&](int t) {                                                  \
      short* ab = (SM) + ((t & 3) << 12);                                      \
      short* bb = (SM) + 16384 + ((t & 3) << 12);                              \
      int kt = t << 5;                                                         \
      gload16((AG) + kt, ab + ldst);                                           \
      gload16((AG) + kt + 64 * 768, ab + ldst + 2048);                         \
      gload16((BG) + kt, bb + ldst);                                           \
      gload16((BG) + kt + 64 * 768, bb + ldst + 2048);                         \
    };                                                                         \
    auto compute = [&](int t) {                                                \
      const short* ab = (SM) + ((t & 3) << 12);                                \
      const short* bb = (SM) + 16384 + ((t & 3) << 12);                        \
      bf16x8 af[4], bf[4];                                                     \
      _Pragma("unroll") for (int mi = 0; mi < 4; ++mi)                         \
          af[mi] = *(const bf16x8*)(ab + ((WR) + mi * 16 + l15) * 32 + fcol);  \
      _Pragma("unroll") for (int ni = 0; ni < 4; ++ni)                         \
          bf[ni] = *(const bf16x8*)(bb + ((WC) + ni * 16 + l15) * 32 + fcol);  \
      __builtin_amdgcn_s_setprio(1);                                           \
      _Pragma("unroll") for (int mi = 0; mi < 4; ++mi)                         \
          _Pragma("unroll") for (int ni = 0; ni < 4; ++ni)                     \
              ACC[mi][ni] = mfma16(af[mi], bf[ni], ACC[mi][ni]);               \
      __builtin_amdgcn_s_setprio(0);                                           \
    };                                                                         \
    stage(0); stage(1); stage(2);                                              \
    SBAR();                                                                    \
    _Pragma("unroll 1") for (int i = 0; i < NT - 3; ++i) {                     \
      SBAR(); WAIT8(); HBAR(); SBAR();                                         \
      stage(i + 3);                                                            \
      SBAR();                                                                  \
      compute(i);                                                              \
    }                                                                          \
    SBAR(); WAIT8(); HBAR(); SBAR(); compute(NT - 3);                          \
    SBAR(); WAIT4(); HBAR(); SBAR(); compute(NT - 2);                          \
    SBAR(); WAIT0(); HBAR(); SBAR(); compute(NT - 1);                          \
  }

// ---------------- QKV projection GEMM ----------------
__global__ __launch_bounds__(256) void gemm_qkv(
    const short* __restrict__ Xb, const short* __restrict__ Wqkv,
    const float* __restrict__ bq, const float* __restrict__ bk,
    const float* __restrict__ bv,
    short* __restrict__ qO, short* __restrict__ kO, short* __restrict__ vT) {
  __shared__ __align__(16) short sm[32768];
  const int tid = threadIdx.x, lane = tid & 63, wid = tid >> 6;
  const int xcd = blockIdx.x & 7, kk = blockIdx.x >> 3;  // kk in [0,144)
  const int m0 = (xcd * 8 + (kk & 7)) * 128;
  const int n0 = (kk >> 3) * 128;
  const int wr = (wid >> 1) * 64, wc = (wid & 1) * 64;
  const int srow = tid >> 2;
  const int scol = (((tid & 3) ^ ((srow >> 1) & 3)) << 3);
  const short* Ag = Xb + (m0 + srow) * 768 + scol;
  const short* Bg = Wqkv + (n0 + srow) * 768 + scol;
  const int ldst = tid * 8;

  const int src = n0 / 768;  // 0=q 1=k 2=v
  const int nloc = n0 % 768;
  float bias[4];
#pragma unroll
  for (int ni = 0; ni < 4; ++ni) {
    int c = nloc + wc + ni * 16 + (lane & 15);
    bias[ni] = (src == 0) ? bq[c] * QSCALE : (src == 1) ? bk[c] : bv[c];
  }
  WAIT0(); SBAR();

  f32x4 acc[4][4] = {};
  GEMM_PIPELINE(sm, Ag, Bg, acc, lane, wr, wc);

  const int bb = m0 >> 12;
  const int s0 = m0 & (SEQ - 1);
  __syncthreads();
  if (src < 2) {
#pragma unroll
    for (int mi = 0; mi < 4; ++mi)
#pragma unroll
      for (int ni = 0; ni < 4; ++ni) {
        int row = wr + mi * 16 + ((lane >> 4) << 2);
        int col = wc + ni * 16 + (lane & 15);
#pragma unroll
        for (int r = 0; r < 4; ++r)
          sm[(row + r) * 132 + col] = f2bf(acc[mi][ni][r] + bias[ni]);
      }
    __syncthreads();
    short* dst = (src == 0) ? qO : kO;
    for (int u = tid; u < 8192; u += 256) {
      int r = u >> 6, cp = (u & 63) << 1;
      unsigned val = *(const unsigned*)&sm[r * 132 + cp];
      int c = nloc + cp;
      int h = c >> 6, d = c & 63;
      *(unsigned*)&dst[(((bb * NH + h) * SEQ) + s0 + r) * DH + d] = val;
    }
  } else {
#pragma unroll
    for (int mi = 0; mi < 4; ++mi)
#pragma unroll
      for (int ni = 0; ni < 4; ++ni) {
        int row = wr + mi * 16 + ((lane >> 4) << 2);
        int col = wc + ni * 16 + (lane & 15);
        short4 pk;
        pk.x = f2bf(acc[mi][ni][0] + bias[ni]);
        pk.y = f2bf(acc[mi][ni][1] + bias[ni]);
        pk.z = f2bf(acc[mi][ni][2] + bias[ni]);
        pk.w = f2bf(acc[mi][ni][3] + bias[ni]);
        *(short4*)&sm[col * 132 + row] = pk;
      }
    __syncthreads();
    for (int u = tid; u < 8192; u += 256) {
      int cc = u >> 6, rp = (u & 63) << 1;
      unsigned val = *(const unsigned*)&sm[cc * 132 + rp];
      int c = nloc + cc;
      int h = c >> 6, d = c & 63;
      *(unsigned*)&vT[(((bb * NH + h) * DH) + d) * SEQ + s0 + rp] = val;
    }
  }
}

// ---------------- sliding-window attention (barrier-free, reg-direct K/V) ----
// 768 blocks (XCD-swizzled), 8 fully independent waves, 16 q-rows each.
// K/V MFMA fragments loaded directly from global (addresses = de-swizzled
// LDS equivalents); no __syncthreads anywhere; per-wave chunk skip.
__global__ __launch_bounds__(512) void attn(
    const short* __restrict__ qI, const short* __restrict__ kI,
    const short* __restrict__ vT, const float* __restrict__ amask,
    short* __restrict__ ctx) {
  __shared__ __align__(16) short Ps[8][16 * 132];
  const int tid = threadIdx.x, lane = tid & 63, wid = tid >> 6;
  const int vb_id = (blockIdx.x & 7) * 96 + (blockIdx.x >> 3);
  const int strip = vb_id & 31;
  const int hh = (vb_id >> 5) % 12;
  const int bb = vb_id / 384;
  const int s0 = strip * 128;
  const int n = s0 >> 8;
  const int i0 = s0 & 255;
  const int base = (n - 1) * 256;
  const int bh = bb * NH + hh;
  const int m = lane & 15, hq = lane >> 4;
  const int iw = i0 + (wid << 4);

  const short* qbase = qI + ((size_t)(bh * SEQ) + s0 + (wid << 4)) * DH;
  const bf16x8 aq0 = *(const bf16x8*)(qbase + m * DH + (hq << 3));
  const bf16x8 aq1 = *(const bf16x8*)(qbase + m * DH + 32 + (hq << 3));

  short* Pw = Ps[wid];
  const int pwr = m * 132;

  // direct-global fragment offsets (shorts)
  const int koff = m * DH + (hq << 3);       // K[key=16jt+m][dh=8hq(+32)]
  const int voff = m * SEQ + (hq << 3);      // V^T[d=16nt+m][key=32ks+8hq]

  const short* kg0 = kI + (size_t)bh * SEQ * DH;
  const short* vg0 = vT + (size_t)bh * DH * SEQ;
  const float* mk0 = amask + bb * SEQ + (hq << 2);

  f32x4 acc[4] = {};
  float mrow = -1e30f, lrow = 0.f;

#pragma unroll 1
  for (int c = 0; c < 6; ++c) {
    const int j0 = c << 7;
    const int kpos0 = base + j0;
    if (kpos0 < 0 || kpos0 >= SEQ) continue;          // OOB chunk (uniform)
    if (j0 + 127 < iw || j0 > iw + 527) continue;     // per-wave band skip

    // QK^T: K fragments straight from global
    const short* kb = kg0 + (size_t)kpos0 * DH + koff;
    f32x4 sc[8];
#pragma unroll
    for (int jt = 0; jt < 8; ++jt) {
      bf16x8 k0 = *(const bf16x8*)(kb + jt * 1024);
      bf16x8 k1 = *(const bf16x8*)(kb + jt * 1024 + 32);
      f32x4 z = {};
      z = mfma16(k0, aq0, z);
      z = mfma16(k1, aq1, z);
      sc[jt] = z;
    }

    // bias + (edge-only) band mask + row max, log2 domain
    const float* mp = mk0 + kpos0;
    float mn = mrow;
    const bool interior = (j0 >= iw + 15) && (j0 <= iw + 385);
    if (interior) {
#pragma unroll
      for (int jt = 0; jt < 8; ++jt) {
        float4 b4 = *(const float4*)(mp + jt * 16);
#pragma unroll
        for (int r = 0; r < 4; ++r) {
          float s = fmaf(-LOG2E, (&b4.x)[r], sc[jt][r]);
          sc[jt][r] = s;
          mn = fmaxf(mn, s);
        }
      }
    } else {
      const int iq = iw + m;
#pragma unroll
      for (int jt = 0; jt < 8; ++jt) {
        float4 b4 = *(const float4*)(mp + jt * 16);
        const int jb = j0 + jt * 16 + (hq << 2);
#pragma unroll
        for (int r = 0; r < 4; ++r) {
          int j = jb + r;
          float s = fmaf(-LOG2E, (&b4.x)[r], sc[jt][r]);
          s = (j >= iq && j <= iq + 512) ? s : NEGV;
          sc[jt][r] = s;
          mn = fmaxf(mn, s);
        }
      }
    }
    mn = fmaxf(mn, __shfl_xor(mn, 16));
    mn = fmaxf(mn, __shfl_xor(mn, 32));

    float l0 = 0.f;
#pragma unroll
    for (int jt = 0; jt < 8; ++jt) {
      float p0 = exp2f(sc[jt][0] - mn);
      float p1 = exp2f(sc[jt][1] - mn);
      float p2 = exp2f(sc[jt][2] - mn);
      float p3 = exp2f(sc[jt][3] - mn);
      l0 += (p0 + p1) + (p2 + p3);
      uint2 u;
      u.x = pack2bf(p0, p1);
      u.y = pack2bf(p2, p3);
      *(uint2*)(Pw + pwr + jt * 16 + (hq << 2)) = u;
    }
    l0 += __shfl_xor(l0, 16);
    l0 += __shfl_xor(l0, 32);
    const float scl = exp2f(mrow - mn);
    lrow = lrow * scl + l0;
    mrow = mn;
    const float s0r = __shfl(scl, (hq << 2) + 0);
    const float s1r = __shfl(scl, (hq << 2) + 1);
    const float s2r = __shfl(scl, (hq << 2) + 2);
    const float s3r = __shfl(scl, (hq << 2) + 3);
#pragma unroll
    for (int nt = 0; nt < 4; ++nt) {
      acc[nt][0] *= s0r; acc[nt][1] *= s1r;
      acc[nt][2] *= s2r; acc[nt][3] *= s3r;
    }

    // fence: this wave's P writes must land before its P reads (rule 18)
    LKWAIT(); SBAR();

    // PV: V fragments straight from global
    const short* vb = vg0 + kpos0 + voff;
#pragma unroll
    for (int ks = 0; ks < 4; ++ks) {
      bf16x8 pa = *(const bf16x8*)(Pw + pwr + ks * 32 + (hq << 3));
#pragma unroll
      for (int nt = 0; nt < 4; ++nt) {
        bf16x8 vv = *(const bf16x8*)(vb + nt * 16 * SEQ + ks * 32);
        acc[nt] = mfma16(pa, vv, acc[nt]);
      }
    }
  }

  // epilogue: normalize, restage via Pw (per-wave), coalesced bf16x8 stores
  const float inv = 1.0f / lrow;
  const float i0r = __shfl(inv, (hq << 2) + 0);
  const float i1r = __shfl(inv, (hq << 2) + 1);
  const float i2r = __shfl(inv, (hq << 2) + 2);
  const float i3r = __shfl(inv, (hq << 2) + 3);
#pragma unroll
  for (int nt = 0; nt < 4; ++nt) {
    Pw[((hq << 2) + 0) * 72 + nt * 16 + m] = f2bf(acc[nt][0] * i0r);
    Pw[((hq << 2) + 1) * 72 + nt * 16 + m] = f2bf(acc[nt][1] * i1r);
    Pw[((hq << 2) + 2) * 72 + nt * 16 + m] = f2bf(acc[nt][2] * i2r);
    Pw[((hq << 2) + 3) * 72 + nt * 16 + m] = f2bf(acc[nt][3] * i3r);
  }
  LKWAIT(); SBAR();
#pragma unroll
  for (int it = 0; it < 2; ++it) {
    int row = it * 8 + (lane >> 3);
    bf16x8 val = *(const bf16x8*)(Pw + row * 72 + ((lane & 7) << 3));
    *(bf16x8*)(ctx + ((size_t)(bb * SEQ) + s0 + (wid << 4) + row) * DM +
               hh * DH + ((lane & 7) << 3)) = val;
  }
}

// ---------------- output projection GEMM (pipelined, 4-buf) ----------------
__global__ __launch_bounds__(256) void gemm_out(
    const short* __restrict__ Cb, const short* __restrict__ Wob,
    const float* __restrict__ bo, float* __restrict__ out) {
  __shared__ __align__(16) short sm[32768];
  const int tid = threadIdx.x, lane = tid & 63, wid = tid >> 6;
  const int xcd = blockIdx.x & 7, kk = blockIdx.x >> 3;  // kk in [0,48)
  const int m0 = (xcd * 8 + (kk & 7)) * 128;
  const int n0 = (kk >> 3) * 128;
  const int wr = (wid >> 1) * 64, wc = (wid & 1) * 64;
  const int srow = tid >> 2;
  const int scol = (((tid & 3) ^ ((srow >> 1) & 3)) << 3);
  const short* Ag = Cb + (m0 + srow) * 768 + scol;
  const short* Bg = Wob + (n0 + srow) * 768 + scol;
  const int ldst = tid * 8;

  float bias[4];
#pragma unroll
  for (int ni = 0; ni < 4; ++ni)
    bias[ni] = bo[n0 + wc + ni * 16 + (lane & 15)];
  WAIT0(); SBAR();

  f32x4 acc[4][4] = {};
  GEMM_PIPELINE(sm, Ag, Bg, acc, lane, wr, wc);

#pragma unroll
  for (int mi = 0; mi < 4; ++mi)
#pragma unroll
    for (int ni = 0; ni < 4; ++ni) {
      int row = m0 + wr + mi * 16 + ((lane >> 4) << 2);
      int col = n0 + wc + ni * 16 + (lane & 15);
#pragma unroll
      for (int r = 0; r < 4; ++r)
        out[(row + r) * DM + col] = acc[mi][ni][r] + bias[ni];
    }
}

// ---------------- launcher ----------------
extern "C" void kernel_launch(void* const* d_in, const int* in_sizes, int n_in,
                              void* d_out, int out_size, void* d_ws, size_t ws_size,
                              hipStream_t stream) {
  (void)in_sizes; (void)n_in; (void)out_size; (void)ws_size;
  const float* hs    = (const float*)d_in[0];
  const float* amask = (const float*)d_in[1];
  const float* Wq = (const float*)d_in[2];
  const float* bq = (const float*)d_in[3];
  const float* Wk = (const float*)d_in[4];
  const float* bk = (const float*)d_in[5];
  const float* Wv = (const float*)d_in[6];
  const float* bv = (const float*)d_in[7];
  const float* Wo = (const float*)d_in[8];
  const float* bo = (const float*)d_in[9];
  float* out = (float*)d_out;
  char* ws = (char*)d_ws;
  short* Xb   = (short*)(ws);
  short* Wqkv = (short*)(ws + 12582912);
  short* Wob  = (short*)(ws + 16121856);
  short* qB   = (short*)(ws + 17301504);
  short* kB   = (short*)(ws + 29884416);
  short* vTB  = (short*)(ws + 42467328);
  short* ctx  = Xb;  // Xb dead after gemm_qkv

  cvt_x<<<dim3(6144), dim3(256), 0, stream>>>(hs, Xb, 8192 * 768 / 4);
  cvt_w<<<dim3(2304), dim3(256), 0, stream>>>(Wq, Wk, Wv, Wo, Wqkv, Wob);
  gemm_qkv<<<dim3(1152), dim3(256), 0, stream>>>(Xb, Wqkv, bq, bk, bv, qB, kB, vTB);
  attn<<<dim3(768), dim3(512), 0, stream>>>(qB, kB, vTB, amask, ctx);
  gemm_out<<<dim3(384), dim3(256), 0, stream>>>(ctx, Wob, bo, out);
}

// Round 15
// 139.534 us; speedup vs baseline: 1.4502x; 1.4502x over previous
//
#include <hip/hip_runtime.h>
#include <hip/hip_bf16.h>
#include <stdint.h>

#define NH 12
#define DH 64
#define SEQ 4096
#define DM 768
#define NEGV -1e9f
#define LOG2E 1.4426950408889634f
#define QSCALE 0.1803368801111601f  // 0.125 * log2(e)

using bf16x8 = __attribute__((ext_vector_type(8))) short;
using f32x4  = __attribute__((ext_vector_type(4))) float;

static __device__ __forceinline__ short f2bf(float f) {
  unsigned u = __builtin_bit_cast(unsigned, f);
  u += 0x7fffu + ((u >> 16) & 1u);
  return (short)(u >> 16);
}

static __device__ __forceinline__ unsigned pack2bf(float lo, float hi) {
  unsigned a = __builtin_bit_cast(unsigned, lo);
  a += 0x7fffu + ((a >> 16) & 1u);
  unsigned b = __builtin_bit_cast(unsigned, hi);
  b += 0x7fffu + ((b >> 16) & 1u);
  return (a >> 16) | (b & 0xffff0000u);
}

static __device__ __forceinline__ void gload16(const void* g, void* l) {
  __builtin_amdgcn_global_load_lds(
      (const __attribute__((address_space(1))) unsigned*)g,
      (__attribute__((address_space(3))) unsigned*)l, 16, 0, 0);
}

static __device__ __forceinline__ f32x4 mfma16(bf16x8 a, bf16x8 b, f32x4 c) {
  return __builtin_amdgcn_mfma_f32_16x16x32_bf16(a, b, c, 0, 0, 0);
}

#define SBAR() __builtin_amdgcn_sched_barrier(0)
#define WAIT8() asm volatile("s_waitcnt vmcnt(8)" ::: "memory")
#define WAIT4() asm volatile("s_waitcnt vmcnt(4)" ::: "memory")
#define WAIT0() asm volatile("s_waitcnt vmcnt(0)" ::: "memory")
#define LKWAIT() asm volatile("s_waitcnt lgkmcnt(0)" ::: "memory")
#define HBAR() __builtin_amdgcn_s_barrier()

// ---------------- conversion kernels ----------------
__global__ __launch_bounds__(256) void cvt_x(const float* __restrict__ X,
                                             short* __restrict__ Xb, int n4) {
  int i = blockIdx.x * 256 + threadIdx.x;
  if (i >= n4) return;
  float4 v = ((const float4*)X)[i];
  short4 o; o.x = f2bf(v.x); o.y = f2bf(v.y); o.z = f2bf(v.z); o.w = f2bf(v.w);
  ((short4*)Xb)[i] = o;
}

__global__ __launch_bounds__(256) void cvt_w(
    const float* __restrict__ Wq, const float* __restrict__ Wk,
    const float* __restrict__ Wv, const float* __restrict__ Wo,
    short* __restrict__ Wqkv, short* __restrict__ Wob) {
  int i = blockIdx.x * 256 + threadIdx.x;  // unit = 4 elems
  const int n1 = 2304 * 768 / 4;
  if (i < n1) {
    int e = i * 4;
    int row = e / 768;
    const float* src;
    float sc = 1.0f;
    if (row < 768)       { src = Wq + e; sc = QSCALE; }
    else if (row < 1536) { src = Wk + e - 768 * 768; }
    else                 { src = Wv + e - 1536 * 768; }
    float4 v = *(const float4*)src;
    short4 o; o.x = f2bf(v.x * sc); o.y = f2bf(v.y * sc);
    o.z = f2bf(v.z * sc); o.w = f2bf(v.w * sc);
    ((short4*)Wqkv)[i] = o;
  } else {
    int j = i - n1;
    if (j >= 768 * 768 / 4) return;
    float4 v = ((const float4*)Wo)[j];
    short4 o; o.x = f2bf(v.x); o.y = f2bf(v.y); o.z = f2bf(v.z); o.w = f2bf(v.w);
    ((short4*)Wob)[j] = o;
  }
}

// ======= pipelined 128x128xBK32 GEMM core (4-buffer, depth-3, counted vmcnt) =======
// (R6 version — measured best)
#define GEMM_PIPELINE(SM, AG, BG, ACC, LANE, WR, WC)                           \
  {                                                                            \
    const int l15 = (LANE) & 15, gw = (LANE) >> 4;                             \
    const int s_ = (l15 >> 1) & 3;                                             \
    const int fcol = ((gw ^ s_) << 3);                                         \
    const int NT = 24; /* 768/32 */                                            \
    auto stage = [&](int t) {                                                  \
      short* ab = (SM) + ((t & 3) << 12);                                      \
      short* bb = (SM) + 16384 + ((t & 3) << 12);                              \
      int kt = t << 5;                                                         \
      gload16((AG) + kt, ab + ldst);                                           \
      gload16((AG) + kt + 64 * 768, ab + ldst + 2048);                         \
      gload16((BG) + kt, bb + ldst);                                           \
      gload16((BG) + kt + 64 * 768, bb + ldst + 2048);                         \
    };                                                                         \
    auto compute = [&](int t) {                                                \
      const short* ab = (SM) + ((t & 3) << 12);                                \
      const short* bb = (SM) + 16384 + ((t & 3) << 12);                        \
      bf16x8 af[4], bf[4];                                                     \
      _Pragma("unroll") for (int mi = 0; mi < 4; ++mi)                         \
          af[mi] = *(const bf16x8*)(ab + ((WR) + mi * 16 + l15) * 32 + fcol);  \
      _Pragma("unroll") for (int ni = 0; ni < 4; ++ni)                         \
          bf[ni] = *(const bf16x8*)(bb + ((WC) + ni * 16 + l15) * 32 + fcol);  \
      __builtin_amdgcn_s_setprio(1);                                           \
      _Pragma("unroll") for (int mi = 0; mi < 4; ++mi)                         \
          _Pragma("unroll") for (int ni = 0; ni < 4; ++ni)                     \
              ACC[mi][ni] = mfma16(af[mi], bf[ni], ACC[mi][ni]);               \
      __builtin_amdgcn_s_setprio(0);                                           \
    };                                                                         \
    stage(0); stage(1); stage(2);                                              \
    SBAR();                                                                    \
    _Pragma("unroll 1") for (int i = 0; i < NT - 3; ++i) {                     \
      SBAR(); WAIT8(); HBAR(); SBAR();                                         \
      stage(i + 3);                                                            \
      SBAR();                                                                  \
      compute(i);                                                              \
    }                                                                          \
    SBAR(); WAIT8(); HBAR(); SBAR(); compute(NT - 3);                          \
    SBAR(); WAIT4(); HBAR(); SBAR(); compute(NT - 2);                          \
    SBAR(); WAIT0(); HBAR(); SBAR(); compute(NT - 1);                          \
  }

// ---------------- QKV projection GEMM ----------------
__global__ __launch_bounds__(256) void gemm_qkv(
    const short* __restrict__ Xb, const short* __restrict__ Wqkv,
    const float* __restrict__ bq, const float* __restrict__ bk,
    const float* __restrict__ bv,
    short* __restrict__ qO, short* __restrict__ kO, short* __restrict__ vT) {
  __shared__ __align__(16) short sm[32768];
  const int tid = threadIdx.x, lane = tid & 63, wid = tid >> 6;
  const int xcd = blockIdx.x & 7, kk = blockIdx.x >> 3;  // kk in [0,144)
  const int m0 = (xcd * 8 + (kk & 7)) * 128;
  const int n0 = (kk >> 3) * 128;
  const int wr = (wid >> 1) * 64, wc = (wid & 1) * 64;
  const int srow = tid >> 2;
  const int scol = (((tid & 3) ^ ((srow >> 1) & 3)) << 3);
  const short* Ag = Xb + (m0 + srow) * 768 + scol;
  const short* Bg = Wqkv + (n0 + srow) * 768 + scol;
  const int ldst = tid * 8;

  const int src = n0 / 768;  // 0=q 1=k 2=v
  const int nloc = n0 % 768;
  float bias[4];
#pragma unroll
  for (int ni = 0; ni < 4; ++ni) {
    int c = nloc + wc + ni * 16 + (lane & 15);
    bias[ni] = (src == 0) ? bq[c] * QSCALE : (src == 1) ? bk[c] : bv[c];
  }
  WAIT0(); SBAR();

  f32x4 acc[4][4] = {};
  GEMM_PIPELINE(sm, Ag, Bg, acc, lane, wr, wc);

  const int bb = m0 >> 12;
  const int s0 = m0 & (SEQ - 1);
  __syncthreads();
  if (src < 2) {
#pragma unroll
    for (int mi = 0; mi < 4; ++mi)
#pragma unroll
      for (int ni = 0; ni < 4; ++ni) {
        int row = wr + mi * 16 + ((lane >> 4) << 2);
        int col = wc + ni * 16 + (lane & 15);
#pragma unroll
        for (int r = 0; r < 4; ++r)
          sm[(row + r) * 132 + col] = f2bf(acc[mi][ni][r] + bias[ni]);
      }
    __syncthreads();
    short* dst = (src == 0) ? qO : kO;
    for (int u = tid; u < 8192; u += 256) {
      int r = u >> 6, cp = (u & 63) << 1;
      unsigned val = *(const unsigned*)&sm[r * 132 + cp];
      int c = nloc + cp;
      int h = c >> 6, d = c & 63;
      *(unsigned*)&dst[(((bb * NH + h) * SEQ) + s0 + r) * DH + d] = val;
    }
  } else {
#pragma unroll
    for (int mi = 0; mi < 4; ++mi)
#pragma unroll
      for (int ni = 0; ni < 4; ++ni) {
        int row = wr + mi * 16 + ((lane >> 4) << 2);
        int col = wc + ni * 16 + (lane & 15);
        short4 pk;
        pk.x = f2bf(acc[mi][ni][0] + bias[ni]);
        pk.y = f2bf(acc[mi][ni][1] + bias[ni]);
        pk.z = f2bf(acc[mi][ni][2] + bias[ni]);
        pk.w = f2bf(acc[mi][ni][3] + bias[ni]);
        *(short4*)&sm[col * 132 + row] = pk;
      }
    __syncthreads();
    for (int u = tid; u < 8192; u += 256) {
      int cc = u >> 6, rp = (u & 63) << 1;
      unsigned val = *(const unsigned*)&sm[cc * 132 + rp];
      int c = nloc + cc;
      int h = c >> 6, d = c & 63;
      *(unsigned*)&vT[(((bb * NH + h) * DH) + d) * SEQ + s0 + rp] = val;
    }
  }
}

// ---------------- sliding-window attention ----------------
// 768 blocks (XCD-swizzled), 4 waves x 32 q-rows (dual Q-fragment) = 128 rows.
// LDS exactly 64KB (Ks 16K + Vs 16K + swizzled P 32K) -> 2 blocks/CU.
// K/V LDS reads amortized over 2 q-subtiles; ballot defer-max; l-reduce in
// epilogue; bias from global (R6-proven).
__global__ __launch_bounds__(256) void attn(
    const short* __restrict__ qI, const short* __restrict__ kI,
    const short* __restrict__ vT, const float* __restrict__ amask,
    short* __restrict__ ctx) {
  __shared__ __align__(16) short Ks[8192];      // [key=128][dh=64] swizzled
  __shared__ __align__(16) short Vs[8192];      // [d=64][key=128] swizzled
  __shared__ __align__(16) short Ps[4][4096];   // [q=32][key=128] XOR-swizzled
  const int tid = threadIdx.x, lane = tid & 63, wid = tid >> 6;
  const int vb_id = (blockIdx.x & 7) * 96 + (blockIdx.x >> 3);
  const int strip = vb_id & 31;
  const int hh = (vb_id >> 5) % 12;
  const int bb = vb_id / 384;
  const int s0 = strip * 128;
  const int n = s0 >> 8;
  const int i0 = s0 & 255;
  const int base = (n - 1) * 256;
  const int bh = bb * NH + hh;
  const int m = lane & 15, hq = lane >> 4;
  const int swz = m & 7;
  const int iw = i0 + (wid << 5);

  // Q fragments: aq[qf][ks] = Q[q = 32*wid + 16*qf + m][dh = 32*ks + 8*hq + e]
  const short* qbase = qI + ((size_t)(bh * SEQ) + s0 + (wid << 5)) * DH;
  bf16x8 aq00 = *(const bf16x8*)(qbase + m * DH + (hq << 3));
  bf16x8 aq01 = *(const bf16x8*)(qbase + m * DH + 32 + (hq << 3));
  bf16x8 aq10 = *(const bf16x8*)(qbase + (16 + m) * DH + (hq << 3));
  bf16x8 aq11 = *(const bf16x8*)(qbase + (16 + m) * DH + 32 + (hq << 3));

  // chunk-invariant LDS read offsets
  const int kb_s0 = m * 64 + ((hq ^ swz) << 3);
  const int kb_s1 = m * 64 + (((hq + 4) ^ swz) << 3);
  const int vk0 = m * 128 + ((hq ^ swz) << 3);
  const int vk1 = m * 128 + (((hq + 4) ^ swz) << 3);
  const int vk2 = m * 128 + (((hq + 8) ^ swz) << 3);
  const int vk3 = m * 128 + (((hq + 12) ^ swz) << 3);
  short* Pw = Ps[wid];
  const int psw = swz << 3;           // P swizzle (short-index XOR, row-keyed)
  const int pwr0 = m * 128;
  const int pwr1 = (16 + m) * 128;

  // staging offsets: 4 passes x 256 thr x 16B for each of K, V
  const int eb = tid * 8;
#define KSRC(p) ({ int e_ = (p)*2048 + eb; int kj_ = e_ >> 6;                 \
                   kj_ * DH + ((((e_ >> 3) & 7) ^ (kj_ & 7)) << 3); })
#define VSRC(p) ({ int e_ = (p)*2048 + eb; int vd_ = e_ >> 7;                 \
                   vd_ * SEQ + ((((e_ >> 3) & 15) ^ (vd_ & 7)) << 3); })
  const int ks0 = KSRC(0), ks1 = KSRC(1), ks2 = KSRC(2), ks3 = KSRC(3);
  const int vs0 = VSRC(0), vs1 = VSRC(1), vs2 = VSRC(2), vs3 = VSRC(3);

  const short* kg0 = kI + (size_t)bh * SEQ * DH;
  const short* vg0 = vT + (size_t)bh * DH * SEQ;
  const float* mk0 = amask + bb * SEQ + (hq << 2);

  // contiguous valid-chunk range (block-uniform)
  int cl0 = (n == 0) ? 2 : 0;
  if (i0 == 128 && cl0 < 1) cl0 = 1;
  int chi = (i0 == 0) ? 4 : 5;
  if (n == 15) chi = 3;

  f32x4 acc0[4] = {}, acc1[4] = {};
  float mrow0 = -1e30f, mrow1 = -1e30f, lrow0 = 0.f, lrow1 = 0.f;

#pragma unroll 1
  for (int cc = cl0; cc <= chi; ++cc) {
    const int j0 = cc << 7;
    const int kpos0 = base + j0;
    __syncthreads();
    {
      const short* kb = kg0 + (size_t)kpos0 * DH;
      gload16(kb + ks0, Ks + eb);
      gload16(kb + ks1, Ks + 2048 + eb);
      gload16(kb + ks2, Ks + 4096 + eb);
      gload16(kb + ks3, Ks + 6144 + eb);
      const short* vbp = vg0 + kpos0;
      gload16(vbp + vs0, Vs + eb);
      gload16(vbp + vs1, Vs + 2048 + eb);
      gload16(vbp + vs2, Vs + 4096 + eb);
      gload16(vbp + vs3, Vs + 6144 + eb);
    }
    __syncthreads();

    // QK^T (swapped, dual q-frag): scq[jt][r] = S[key=16jt+4hq+r][q=16qf+m]
    f32x4 sc0[8], sc1[8];
    __builtin_amdgcn_s_setprio(1);
#pragma unroll
    for (int jt = 0; jt < 8; ++jt) {
      bf16x8 k0 = *(const bf16x8*)(Ks + jt * 1024 + kb_s0);
      bf16x8 k1 = *(const bf16x8*)(Ks + jt * 1024 + kb_s1);
      f32x4 z0 = {}, z1 = {};
      z0 = mfma16(k0, aq00, z0);
      z0 = mfma16(k1, aq01, z0);
      z1 = mfma16(k0, aq10, z1);
      z1 = mfma16(k1, aq11, z1);
      sc0[jt] = z0;
      sc1[jt] = z1;
    }
    __builtin_amdgcn_s_setprio(0);

    // bias (global) + (edge-only) band mask + per-lane max, log2 domain
    const float* mp = mk0 + kpos0;
    const bool interior = (j0 >= iw + 31) && (j0 <= iw + 385);
    float mp0[4] = {-3e38f, -3e38f, -3e38f, -3e38f};
    float mp1[4] = {-3e38f, -3e38f, -3e38f, -3e38f};
    if (interior) {
#pragma unroll
      for (int jt = 0; jt < 8; ++jt) {
        float4 b4 = *(const float4*)(mp + jt * 16);
#pragma unroll
        for (int r = 0; r < 4; ++r) {
          float s0v = fmaf(-LOG2E, (&b4.x)[r], sc0[jt][r]);
          float s1v = fmaf(-LOG2E, (&b4.x)[r], sc1[jt][r]);
          sc0[jt][r] = s0v; mp0[r] = fmaxf(mp0[r], s0v);
          sc1[jt][r] = s1v; mp1[r] = fmaxf(mp1[r], s1v);
        }
      }
    } else {
      const int iq0 = iw + m, iq1 = iw + 16 + m;
#pragma unroll
      for (int jt = 0; jt < 8; ++jt) {
        float4 b4 = *(const float4*)(mp + jt * 16);
        const int jb = j0 + jt * 16 + (hq << 2);
#pragma unroll
        for (int r = 0; r < 4; ++r) {
          int j = jb + r;
          float s0v = fmaf(-LOG2E, (&b4.x)[r], sc0[jt][r]);
          float s1v = fmaf(-LOG2E, (&b4.x)[r], sc1[jt][r]);
          s0v = (j >= iq0 && j <= iq0 + 512) ? s0v : NEGV;
          s1v = (j >= iq1 && j <= iq1 + 512) ? s1v : NEGV;
          sc0[jt][r] = s0v; mp0[r] = fmaxf(mp0[r], s0v);
          sc1[jt][r] = s1v; mp1[r] = fmaxf(mp1[r], s1v);
        }
      }
    }
    const float mx0 = fmaxf(fmaxf(mp0[0], mp0[1]), fmaxf(mp0[2], mp0[3]));
    const float mx1 = fmaxf(fmaxf(mp1[0], mp1[1]), fmaxf(mp1[2], mp1[3]));

    // ballot defer-max: full reduce+rescale only when bound exceeded
    const bool resc = __any((mx0 > mrow0 + 8.0f) | (mx1 > mrow1 + 8.0f));
    float scl0 = 1.f, scl1 = 1.f;
    if (resc) {
      float mn0 = fmaxf(mrow0, mx0), mn1 = fmaxf(mrow1, mx1);
      mn0 = fmaxf(mn0, __shfl_xor(mn0, 16));
      mn0 = fmaxf(mn0, __shfl_xor(mn0, 32));
      mn1 = fmaxf(mn1, __shfl_xor(mn1, 16));
      mn1 = fmaxf(mn1, __shfl_xor(mn1, 32));
      scl0 = exp2f(mrow0 - mn0);
      scl1 = exp2f(mrow1 - mn1);
      mrow0 = mn0; mrow1 = mn1;
    }

    // exp2 + pack P into swizzled LDS; per-lane partial l sums
    float l0a = 0.f, l0b = 0.f;
#pragma unroll
    for (int jt = 0; jt < 8; ++jt) {
      float p0 = exp2f(sc0[jt][0] - mrow0);
      float p1 = exp2f(sc0[jt][1] - mrow0);
      float p2 = exp2f(sc0[jt][2] - mrow0);
      float p3 = exp2f(sc0[jt][3] - mrow0);
      l0a += (p0 + p1) + (p2 + p3);
      uint2 u;
      u.x = pack2bf(p0, p1);
      u.y = pack2bf(p2, p3);
      *(uint2*)(Pw + ((pwr0 + jt * 16 + (hq << 2)) ^ psw)) = u;
      float q0 = exp2f(sc1[jt][0] - mrow1);
      float q1 = exp2f(sc1[jt][1] - mrow1);
      float q2 = exp2f(sc1[jt][2] - mrow1);
      float q3 = exp2f(sc1[jt][3] - mrow1);
      l0b += (q0 + q1) + (q2 + q3);
      uint2 w;
      w.x = pack2bf(q0, q1);
      w.y = pack2bf(q2, q3);
      *(uint2*)(Pw + ((pwr1 + jt * 16 + (hq << 2)) ^ psw)) = w;
    }
    if (resc) {
      lrow0 = lrow0 * scl0 + l0a;
      lrow1 = lrow1 * scl1 + l0b;
      float sa[4], sb[4];
#pragma unroll
      for (int r = 0; r < 4; ++r) {
        sa[r] = __shfl(scl0, (hq << 2) + r);
        sb[r] = __shfl(scl1, (hq << 2) + r);
      }
#pragma unroll
      for (int nt = 0; nt < 4; ++nt)
#pragma unroll
        for (int r = 0; r < 4; ++r) {
          acc0[nt][r] *= sa[r];
          acc1[nt][r] *= sb[r];
        }
    } else {
      lrow0 += l0a;
      lrow1 += l0b;
    }

    // fence: this wave's P writes must land before its P reads (rule 18)
    LKWAIT(); SBAR();

    // PV (V fragments shared across both q-subtiles)
    __builtin_amdgcn_s_setprio(1);
#pragma unroll
    for (int ks = 0; ks < 4; ++ks) {
      const int vkk = (ks == 0) ? vk0 : (ks == 1) ? vk1 : (ks == 2) ? vk2 : vk3;
      bf16x8 pa0 = *(const bf16x8*)(Pw + ((pwr0 + ks * 32 + (hq << 3)) ^ psw));
      bf16x8 pa1 = *(const bf16x8*)(Pw + ((pwr1 + ks * 32 + (hq << 3)) ^ psw));
#pragma unroll
      for (int nt = 0; nt < 4; ++nt) {
        bf16x8 vv = *(const bf16x8*)(Vs + nt * 2048 + vkk);
        acc0[nt] = mfma16(pa0, vv, acc0[nt]);
        acc1[nt] = mfma16(pa1, vv, acc1[nt]);
      }
    }
    __builtin_amdgcn_s_setprio(0);
  }

  // epilogue: deferred l-reduce, normalize, restage, coalesced stores
  lrow0 += __shfl_xor(lrow0, 16);
  lrow0 += __shfl_xor(lrow0, 32);
  lrow1 += __shfl_xor(lrow1, 16);
  lrow1 += __shfl_xor(lrow1, 32);
  const float inv0 = 1.0f / lrow0;
  const float inv1 = 1.0f / lrow1;
  float ia[4], ib[4];
#pragma unroll
  for (int r = 0; r < 4; ++r) {
    ia[r] = __shfl(inv0, (hq << 2) + r);
    ib[r] = __shfl(inv1, (hq << 2) + r);
  }
  __syncthreads();
  short* cw = Pw;
#pragma unroll
  for (int nt = 0; nt < 4; ++nt)
#pragma unroll
    for (int r = 0; r < 4; ++r) {
      cw[((hq << 2) + r) * 72 + nt * 16 + m] = f2bf(acc0[nt][r] * ia[r]);
      cw[(16 + (hq << 2) + r) * 72 + nt * 16 + m] = f2bf(acc1[nt][r] * ib[r]);
    }
  LKWAIT(); SBAR();
#pragma unroll
  for (int it = 0; it < 4; ++it) {
    int row = it * 8 + (lane >> 3);
    bf16x8 val = *(const bf16x8*)(cw + row * 72 + ((lane & 7) << 3));
    *(bf16x8*)(ctx + ((size_t)(bb * SEQ) + s0 + (wid << 5) + row) * DM +
               hh * DH + ((lane & 7) << 3)) = val;
  }
}

// ---------------- output projection GEMM (pipelined, 4-buf) ----------------
__global__ __launch_bounds__(256) void gemm_out(
    const short* __restrict__ Cb, const short* __restrict__ Wob,
    const float* __restrict__ bo, float* __restrict__ out) {
  __shared__ __align__(16) short sm[32768];
  const int tid = threadIdx.x, lane = tid & 63, wid = tid >> 6;
  const int xcd = blockIdx.x & 7, kk = blockIdx.x >> 3;  // kk in [0,48)
  const int m0 = (xcd * 8 + (kk & 7)) * 128;
  const int n0 = (kk >> 3) * 128;
  const int wr = (wid >> 1) * 64, wc = (wid & 1) * 64;
  const int srow = tid >> 2;
  const int scol = (((tid & 3) ^ ((srow >> 1) & 3)) << 3);
  const short* Ag = Cb + (m0 + srow) * 768 + scol;
  const short* Bg = Wob + (n0 + srow) * 768 + scol;
  const int ldst = tid * 8;

  float bias[4];
#pragma unroll
  for (int ni = 0; ni < 4; ++ni)
    bias[ni] = bo[n0 + wc + ni * 16 + (lane & 15)];
  WAIT0(); SBAR();

  f32x4 acc[4][4] = {};
  GEMM_PIPELINE(sm, Ag, Bg, acc, lane, wr, wc);

#pragma unroll
  for (int mi = 0; mi < 4; ++mi)
#pragma unroll
    for (int ni = 0; ni < 4; ++ni) {
      int row = m0 + wr + mi * 16 + ((lane >> 4) << 2);
      int col = n0 + wc + ni * 16 + (lane & 15);
#pragma unroll
      for (int r = 0; r < 4; ++r)
        out[(row + r) * DM + col] = acc[mi][ni][r] + bias[ni];
    }
}

// ---------------- launcher ----------------
extern "C" void kernel_launch(void* const* d_in, const int* in_sizes, int n_in,
                              void* d_out, int out_size, void* d_ws, size_t ws_size,
                              hipStream_t stream) {
  (void)in_sizes; (void)n_in; (void)out_size; (void)ws_size;
  const float* hs    = (const float*)d_in[0];
  const float* amask = (const float*)d_in[1];
  const float* Wq = (const float*)d_in[2];
  const float* bq = (const float*)d_in[3];
  const float* Wk = (const float*)d_in[4];
  const float* bk = (const float*)d_in[5];
  const float* Wv = (const float*)d_in[6];
  const float* bv = (const float*)d_in[7];
  const float* Wo = (const float*)d_in[8];
  const float* bo = (const float*)d_in[9];
  float* out = (float*)d_out;
  char* ws = (char*)d_ws;
  short* Xb   = (short*)(ws);
  short* Wqkv = (short*)(ws + 12582912);
  short* Wob  = (short*)(ws + 16121856);
  short* qB   = (short*)(ws + 17301504);
  short* kB   = (short*)(ws + 29884416);
  short* vTB  = (short*)(ws + 42467328);
  short* ctx  = Xb;  // Xb dead after gemm_qkv

  cvt_x<<<dim3(6144), dim3(256), 0, stream>>>(hs, Xb, 8192 * 768 / 4);
  cvt_w<<<dim3(2304), dim3(256), 0, stream>>>(Wq, Wk, Wv, Wo, Wqkv, Wob);
  gemm_qkv<<<dim3(1152), dim3(256), 0, stream>>>(Xb, Wqkv, bq, bk, bv, qB, kB, vTB);
  attn<<<dim3(768), dim3(256), 0, stream>>>(qB, kB, vTB, amask, ctx);
  gemm_out<<<dim3(384), dim3(256), 0, stream>>>(ctx, Wob, bo, out);
}

// Round 16
// 131.374 us; speedup vs baseline: 1.5402x; 1.0621x over previous
//
#include <hip/hip_runtime.h>
#include <hip/hip_bf16.h>
#include <stdint.h>

#define NH 12
#define DH 64
#define SEQ 4096
#define DM 768
#define NEGV -1e9f
#define LOG2E 1.4426950408889634f
#define QSCALE 0.1803368801111601f  // 0.125 * log2(e)

using bf16x8 = __attribute__((ext_vector_type(8))) short;
using f32x4  = __attribute__((ext_vector_type(4))) float;

static __device__ __forceinline__ short f2bf(float f) {
  unsigned u = __builtin_bit_cast(unsigned, f);
  u += 0x7fffu + ((u >> 16) & 1u);
  return (short)(u >> 16);
}

static __device__ __forceinline__ unsigned pack2bf(float lo, float hi) {
  unsigned a = __builtin_bit_cast(unsigned, lo);
  a += 0x7fffu + ((a >> 16) & 1u);
  unsigned b = __builtin_bit_cast(unsigned, hi);
  b += 0x7fffu + ((b >> 16) & 1u);
  return (a >> 16) | (b & 0xffff0000u);
}

static __device__ __forceinline__ void gload16(const void* g, void* l) {
  __builtin_amdgcn_global_load_lds(
      (const __attribute__((address_space(1))) unsigned*)g,
      (__attribute__((address_space(3))) unsigned*)l, 16, 0, 0);
}

static __device__ __forceinline__ f32x4 mfma16(bf16x8 a, bf16x8 b, f32x4 c) {
  return __builtin_amdgcn_mfma_f32_16x16x32_bf16(a, b, c, 0, 0, 0);
}

#define SBAR() __builtin_amdgcn_sched_barrier(0)
#define WAIT8() asm volatile("s_waitcnt vmcnt(8)" ::: "memory")
#define WAIT0() asm volatile("s_waitcnt vmcnt(0)" ::: "memory")
#define HBAR() __builtin_amdgcn_s_barrier()

// ---------------- conversion kernels ----------------
__global__ __launch_bounds__(256) void cvt_x(const float* __restrict__ X,
                                             short* __restrict__ Xb, int n4) {
  int i = blockIdx.x * 256 + threadIdx.x;
  if (i >= n4) return;
  float4 v = ((const float4*)X)[i];
  short4 o; o.x = f2bf(v.x); o.y = f2bf(v.y); o.z = f2bf(v.z); o.w = f2bf(v.w);
  ((short4*)Xb)[i] = o;
}

__global__ __launch_bounds__(256) void cvt_w(
    const float* __restrict__ Wq, const float* __restrict__ Wk,
    const float* __restrict__ Wv, const float* __restrict__ Wo,
    short* __restrict__ Wqkv, short* __restrict__ Wob) {
  int i = blockIdx.x * 256 + threadIdx.x;  // unit = 4 elems
  const int n1 = 2304 * 768 / 4;
  if (i < n1) {
    int e = i * 4;
    int row = e / 768;
    const float* src;
    float sc = 1.0f;
    if (row < 768)       { src = Wq + e; sc = QSCALE; }
    else if (row < 1536) { src = Wk + e - 768 * 768; }
    else                 { src = Wv + e - 1536 * 768; }
    float4 v = *(const float4*)src;
    short4 o; o.x = f2bf(v.x * sc); o.y = f2bf(v.y * sc);
    o.z = f2bf(v.z * sc); o.w = f2bf(v.w * sc);
    ((short4*)Wqkv)[i] = o;
  } else {
    int j = i - n1;
    if (j >= 768 * 768 / 4) return;
    float4 v = ((const float4*)Wo)[j];
    short4 o; o.x = f2bf(v.x); o.y = f2bf(v.y); o.z = f2bf(v.z); o.w = f2bf(v.w);
    ((short4*)Wob)[j] = o;
  }
}

// ======= pipelined 128x128 GEMM core, BK=64, 2-buffer, counted vmcnt =======
// LDS 64KB: A bufs sm[0..16383] (2 x 8192 shorts), B bufs sm[16384..32767].
// stage = 8 gload16. Prologue stages 0,1 (16 outstanding). Per iter:
// vmcnt(8) retires oldest tile's 8 (next tile's 8 stay in flight across
// barrier); compute (32 MFMA/wave); barrier; stage(i+2) into freed buf.
// Final iter vmcnt(0). Swizzle key (row>>1)&3 both sides (rule #21).
#define GEMM_PIPELINE(SM, AG, BG, ACC, LANE, WR, WC)                           \
  {                                                                            \
    const int l15 = (LANE) & 15, gw = (LANE) >> 4;                             \
    const int s_ = (l15 >> 1) & 3;                                             \
    const int NT = 12; /* 768/64 */                                            \
    auto stage = [&](int t) {                                                  \
      short* ab = (SM) + ((t & 1) << 13);                                      \
      short* bb = (SM) + 16384 + ((t & 1) << 13);                              \
      int kt = t << 6;                                                         \
      gload16((AG) + kt, ab + ldst);                                           \
      gload16((AG) + kt + 32 * 768, ab + ldst + 2048);                         \
      gload16((AG) + kt + 64 * 768, ab + ldst + 4096);                         \
      gload16((AG) + kt + 96 * 768, ab + ldst + 6144);                         \
      gload16((BG) + kt, bb + ldst);                                           \
      gload16((BG) + kt + 32 * 768, bb + ldst + 2048);                         \
      gload16((BG) + kt + 64 * 768, bb + ldst + 4096);                         \
      gload16((BG) + kt + 96 * 768, bb + ldst + 6144);                         \
    };                                                                         \
    auto compute = [&](int t) {                                                \
      const short* ab = (SM) + ((t & 1) << 13);                                \
      const short* bb = (SM) + 16384 + ((t & 1) << 13);                        \
      _Pragma("unroll") for (int kk = 0; kk < 2; ++kk) {                       \
        const int fc = (((kk << 2) + (gw ^ s_)) << 3);                         \
        bf16x8 af[4], bf[4];                                                   \
        _Pragma("unroll") for (int mi = 0; mi < 4; ++mi)                       \
            af[mi] = *(const bf16x8*)(ab + ((WR) + mi * 16 + l15) * 64 + fc);  \
        _Pragma("unroll") for (int ni = 0; ni < 4; ++ni)                       \
            bf[ni] = *(const bf16x8*)(bb + ((WC) + ni * 16 + l15) * 64 + fc);  \
        __builtin_amdgcn_s_setprio(1);                                         \
        _Pragma("unroll") for (int mi = 0; mi < 4; ++mi)                       \
            _Pragma("unroll") for (int ni = 0; ni < 4; ++ni)                   \
                ACC[mi][ni] = mfma16(af[mi], bf[ni], ACC[mi][ni]);             \
        __builtin_amdgcn_s_setprio(0);                                         \
      }                                                                        \
    };                                                                         \
    stage(0); stage(1);                                                        \
    SBAR();                                                                    \
    _Pragma("unroll 1") for (int i = 0; i < NT; ++i) {                         \
      SBAR();                                                                  \
      if (i < NT - 1) { WAIT8(); } else { WAIT0(); }                           \
      HBAR(); SBAR();                                                          \
      compute(i);                                                              \
      SBAR(); HBAR();                                                          \
      if (i + 2 < NT) stage(i + 2);                                            \
    }                                                                          \
  }

// ---------------- QKV projection GEMM ----------------
// 1D grid 1152, XCD-chunked: each XCD owns an 8-m-block A panel x all 18 n.
__global__ __launch_bounds__(256) void gemm_qkv(
    const short* __restrict__ Xb, const short* __restrict__ Wqkv,
    const float* __restrict__ bq, const float* __restrict__ bk,
    const float* __restrict__ bv,
    short* __restrict__ qO, short* __restrict__ kO, short* __restrict__ vT) {
  __shared__ __align__(16) short sm[32768];
  const int tid = threadIdx.x, lane = tid & 63, wid = tid >> 6;
  const int xcd = blockIdx.x & 7, kk = blockIdx.x >> 3;  // kk in [0,144)
  const int m0 = (xcd * 8 + (kk & 7)) * 128;
  const int n0 = (kk >> 3) * 128;
  const int wr = (wid >> 1) * 64, wc = (wid & 1) * 64;
  const int srow = tid >> 3;                                    // 0..31
  const int scol = (((tid & 7) ^ ((tid >> 4) & 3)) << 3);       // swizzled granule
  const short* Ag = Xb + (m0 + srow) * 768 + scol;
  const short* Bg = Wqkv + (n0 + srow) * 768 + scol;
  const int ldst = tid * 8;

  // bias loads BEFORE pipeline, then drain so vmcnt counting stays exact
  const int src = n0 / 768;  // 0=q 1=k 2=v
  const int nloc = n0 % 768;
  float bias[4];
#pragma unroll
  for (int ni = 0; ni < 4; ++ni) {
    int c = nloc + wc + ni * 16 + (lane & 15);
    bias[ni] = (src == 0) ? bq[c] * QSCALE : (src == 1) ? bk[c] : bv[c];
  }
  WAIT0(); SBAR();

  f32x4 acc[4][4] = {};
  GEMM_PIPELINE(sm, Ag, Bg, acc, lane, wr, wc);

  const int bb = m0 >> 12;
  const int s0 = m0 & (SEQ - 1);
  __syncthreads();
  if (src < 2) {
#pragma unroll
    for (int mi = 0; mi < 4; ++mi)
#pragma unroll
      for (int ni = 0; ni < 4; ++ni) {
        int row = wr + mi * 16 + ((lane >> 4) << 2);
        int col = wc + ni * 16 + (lane & 15);
#pragma unroll
        for (int r = 0; r < 4; ++r)
          sm[(row + r) * 132 + col] = f2bf(acc[mi][ni][r] + bias[ni]);
      }
    __syncthreads();
    short* dst = (src == 0) ? qO : kO;
    for (int u = tid; u < 8192; u += 256) {
      int r = u >> 6, cp = (u & 63) << 1;
      unsigned val = *(const unsigned*)&sm[r * 132 + cp];
      int c = nloc + cp;
      int h = c >> 6, d = c & 63;
      *(unsigned*)&dst[(((bb * NH + h) * SEQ) + s0 + r) * DH + d] = val;
    }
  } else {
#pragma unroll
    for (int mi = 0; mi < 4; ++mi)
#pragma unroll
      for (int ni = 0; ni < 4; ++ni) {
        int row = wr + mi * 16 + ((lane >> 4) << 2);
        int col = wc + ni * 16 + (lane & 15);
        short4 pk;
        pk.x = f2bf(acc[mi][ni][0] + bias[ni]);
        pk.y = f2bf(acc[mi][ni][1] + bias[ni]);
        pk.z = f2bf(acc[mi][ni][2] + bias[ni]);
        pk.w = f2bf(acc[mi][ni][3] + bias[ni]);
        *(short4*)&sm[col * 132 + row] = pk;
      }
    __syncthreads();
    for (int u = tid; u < 8192; u += 256) {
      int cc = u >> 6, rp = (u & 63) << 1;
      unsigned val = *(const unsigned*)&sm[cc * 132 + rp];
      int c = nloc + cc;
      int h = c >> 6, d = c & 63;
      *(unsigned*)&vT[(((bb * NH + h) * DH) + d) * SEQ + s0 + rp] = val;
    }
  }
}

// ---------------- sliding-window attention (R6-exact, best measured) --------
__global__ __launch_bounds__(512, 4) void attn(
    const short* __restrict__ qI, const short* __restrict__ kI,
    const short* __restrict__ vT, const float* __restrict__ amask,
    short* __restrict__ ctx) {
  __shared__ __align__(16) short Ks[128 * 64];
  __shared__ __align__(16) short Vs[64 * 128];
  __shared__ __align__(16) short Ps[8][16 * 132];
  const int tid = threadIdx.x, lane = tid & 63, wid = tid >> 6;
  const int vb_id = (blockIdx.x & 7) * 96 + (blockIdx.x >> 3);
  const int strip = vb_id & 31;
  const int hh = (vb_id >> 5) % 12;
  const int bb = vb_id / 384;
  const int s0 = strip * 128;
  const int n = s0 >> 8;
  const int i0 = s0 & 255;
  const int bh = bb * NH + hh;
  const int m = lane & 15, hq = lane >> 4;
  const int swz = m & 7;
  const int iw = i0 + (wid << 4);

  const short* qbase = qI + ((size_t)(bh * SEQ) + s0 + (wid << 4)) * DH;
  const bf16x8 aq0 = *(const bf16x8*)(qbase + m * DH + (hq << 3));
  const bf16x8 aq1 = *(const bf16x8*)(qbase + m * DH + 32 + (hq << 3));

  const int kb_s0 = m * 64 + ((hq ^ swz) << 3);
  const int kb_s1 = m * 64 + (((hq + 4) ^ swz) << 3);
  const int vk0 = m * 128 + ((hq ^ swz) << 3);
  const int vk1 = m * 128 + (((hq + 4) ^ swz) << 3);
  const int vk2 = m * 128 + (((hq + 8) ^ swz) << 3);
  const int vk3 = m * 128 + (((hq + 12) ^ swz) << 3);
  short* Pw = Ps[wid];
  const int pwr = m * 132;

  const int e0 = tid * 8, e1 = tid * 8 + 4096;
  const int kj0 = e0 >> 6, kj1 = e1 >> 6;
  const int ksrc0 = kj0 * DH + ((((e0 >> 3) & 7) ^ (kj0 & 7)) << 3);
  const int ksrc1 = kj1 * DH + ((((e1 >> 3) & 7) ^ (kj1 & 7)) << 3);
  const int vd0 = e0 >> 7, vd1 = e1 >> 7;
  const int vsrc0 = vd0 * SEQ + ((((e0 >> 3) & 15) ^ (vd0 & 7)) << 3);
  const int vsrc1 = vd1 * SEQ + ((((e1 >> 3) & 15) ^ (vd1 & 7)) << 3);

  const short* kg0 = kI + (size_t)bh * SEQ * DH;
  const short* vg0 = vT + (size_t)bh * DH * SEQ;
  const float* mk0 = amask + bb * SEQ + (hq << 2);

  f32x4 acc[4] = {};
  float mrow = -1e30f, lrow = 0.f;

#pragma unroll 1
  for (int c = 0; c < 6; ++c) {
    const int j0 = c << 7;
    const int kpos0 = ((n - 1) << 8) + j0;
    if (kpos0 < 0 || kpos0 >= SEQ) continue;
    if (j0 + 127 < i0 || j0 > i0 + 639) continue;

    __syncthreads();
    {
      const short* kb = kg0 + (size_t)kpos0 * DH;
      gload16(kb + ksrc0, (short*)Ks + e0);
      gload16(kb + ksrc1, (short*)Ks + e1);
      const short* vbp = vg0 + kpos0;
      gload16(vbp + vsrc0, (short*)Vs + e0);
      gload16(vbp + vsrc1, (short*)Vs + e1);
    }
    __syncthreads();

    f32x4 sc[8];
    __builtin_amdgcn_s_setprio(1);
#pragma unroll
    for (int jt = 0; jt < 8; ++jt) {
      bf16x8 k0 = *(const bf16x8*)(Ks + jt * 1024 + kb_s0);
      bf16x8 k1 = *(const bf16x8*)(Ks + jt * 1024 + kb_s1);
      f32x4 z = {};
      z = mfma16(k0, aq0, z);
      z = mfma16(k1, aq1, z);
      sc[jt] = z;
    }
    __builtin_amdgcn_s_setprio(0);

    const float* mp = mk0 + kpos0;
    float mn = mrow;
    const bool interior = (j0 >= iw + 15) && (j0 <= iw + 385);
    if (interior) {
#pragma unroll
      for (int jt = 0; jt < 8; ++jt) {
        float4 b4 = *(const float4*)(mp + jt * 16);
#pragma unroll
        for (int r = 0; r < 4; ++r) {
          float s = fmaf(-LOG2E, (&b4.x)[r], sc[jt][r]);
          sc[jt][r] = s;
          mn = fmaxf(mn, s);
        }
      }
    } else {
      const int iq = iw + m;
#pragma unroll
      for (int jt = 0; jt < 8; ++jt) {
        float4 b4 = *(const float4*)(mp + jt * 16);
        const int jb = j0 + jt * 16 + (hq << 2);
#pragma unroll
        for (int r = 0; r < 4; ++r) {
          int j = jb + r;
          float s = fmaf(-LOG2E, (&b4.x)[r], sc[jt][r]);
          s = (j >= iq && j <= iq + 512) ? s : NEGV;
          sc[jt][r] = s;
          mn = fmaxf(mn, s);
        }
      }
    }
    mn = fmaxf(mn, __shfl_xor(mn, 16));
    mn = fmaxf(mn, __shfl_xor(mn, 32));

    float l0 = 0.f;
#pragma unroll
    for (int jt = 0; jt < 8; ++jt) {
      float p0 = exp2f(sc[jt][0] - mn);
      float p1 = exp2f(sc[jt][1] - mn);
      float p2 = exp2f(sc[jt][2] - mn);
      float p3 = exp2f(sc[jt][3] - mn);
      l0 += (p0 + p1) + (p2 + p3);
      uint2 u;
      u.x = pack2bf(p0, p1);
      u.y = pack2bf(p2, p3);
      *(uint2*)(Pw + pwr + jt * 16 + (hq << 2)) = u;
    }
    l0 += __shfl_xor(l0, 16);
    l0 += __shfl_xor(l0, 32);
    const float scl = exp2f(mrow - mn);
    lrow = lrow * scl + l0;
    mrow = mn;
    const float s0r = __shfl(scl, (hq << 2) + 0);
    const float s1r = __shfl(scl, (hq << 2) + 1);
    const float s2r = __shfl(scl, (hq << 2) + 2);
    const float s3r = __shfl(scl, (hq << 2) + 3);
#pragma unroll
    for (int nt = 0; nt < 4; ++nt) {
      acc[nt][0] *= s0r; acc[nt][1] *= s1r;
      acc[nt][2] *= s2r; acc[nt][3] *= s3r;
    }

    asm volatile("s_waitcnt lgkmcnt(0)" ::: "memory");
    __builtin_amdgcn_sched_barrier(0);

    __builtin_amdgcn_s_setprio(1);
#pragma unroll
    for (int ks = 0; ks < 4; ++ks) {
      bf16x8 pa = *(const bf16x8*)(Pw + pwr + ks * 32 + (hq << 3));
      const int vkk = (ks == 0) ? vk0 : (ks == 1) ? vk1 : (ks == 2) ? vk2 : vk3;
#pragma unroll
      for (int nt = 0; nt < 4; ++nt) {
        bf16x8 vv = *(const bf16x8*)(Vs + nt * 2048 + vkk);
        acc[nt] = mfma16(pa, vv, acc[nt]);
      }
    }
    __builtin_amdgcn_s_setprio(0);
  }

  const float inv = 1.0f / lrow;
  const float i0r = __shfl(inv, (hq << 2) + 0);
  const float i1r = __shfl(inv, (hq << 2) + 1);
  const float i2r = __shfl(inv, (hq << 2) + 2);
  const float i3r = __shfl(inv, (hq << 2) + 3);
#pragma unroll
  for (int nt = 0; nt < 4; ++nt) {
    Pw[((hq << 2) + 0) * 72 + nt * 16 + m] = f2bf(acc[nt][0] * i0r);
    Pw[((hq << 2) + 1) * 72 + nt * 16 + m] = f2bf(acc[nt][1] * i1r);
    Pw[((hq << 2) + 2) * 72 + nt * 16 + m] = f2bf(acc[nt][2] * i2r);
    Pw[((hq << 2) + 3) * 72 + nt * 16 + m] = f2bf(acc[nt][3] * i3r);
  }
  asm volatile("s_waitcnt lgkmcnt(0)" ::: "memory");
  __builtin_amdgcn_sched_barrier(0);
#pragma unroll
  for (int it = 0; it < 2; ++it) {
    int row = it * 8 + (lane >> 3);
    bf16x8 val = *(const bf16x8*)(Pw + row * 72 + ((lane & 7) << 3));
    *(bf16x8*)(ctx + ((size_t)(bb * SEQ) + s0 + (wid << 4) + row) * DM +
               hh * DH + ((lane & 7) << 3)) = val;
  }
}

// ---------------- output projection GEMM (BK=64 pipelined) ----------------
__global__ __launch_bounds__(256) void gemm_out(
    const short* __restrict__ Cb, const short* __restrict__ Wob,
    const float* __restrict__ bo, float* __restrict__ out) {
  __shared__ __align__(16) short sm[32768];
  const int tid = threadIdx.x, lane = tid & 63, wid = tid >> 6;
  const int xcd = blockIdx.x & 7, kk = blockIdx.x >> 3;  // kk in [0,48)
  const int m0 = (xcd * 8 + (kk & 7)) * 128;
  const int n0 = (kk >> 3) * 128;
  const int wr = (wid >> 1) * 64, wc = (wid & 1) * 64;
  const int srow = tid >> 3;
  const int scol = (((tid & 7) ^ ((tid >> 4) & 3)) << 3);
  const short* Ag = Cb + (m0 + srow) * 768 + scol;
  const short* Bg = Wob + (n0 + srow) * 768 + scol;
  const int ldst = tid * 8;

  float bias[4];
#pragma unroll
  for (int ni = 0; ni < 4; ++ni)
    bias[ni] = bo[n0 + wc + ni * 16 + (lane & 15)];
  WAIT0(); SBAR();

  f32x4 acc[4][4] = {};
  GEMM_PIPELINE(sm, Ag, Bg, acc, lane, wr, wc);

#pragma unroll
  for (int mi = 0; mi < 4; ++mi)
#pragma unroll
    for (int ni = 0; ni < 4; ++ni) {
      int row = m0 + wr + mi * 16 + ((lane >> 4) << 2);
      int col = n0 + wc + ni * 16 + (lane & 15);
#pragma unroll
      for (int r = 0; r < 4; ++r)
        out[(row + r) * DM + col] = acc[mi][ni][r] + bias[ni];
    }
}

// ---------------- launcher ----------------
extern "C" void kernel_launch(void* const* d_in, const int* in_sizes, int n_in,
                              void* d_out, int out_size, void* d_ws, size_t ws_size,
                              hipStream_t stream) {
  (void)in_sizes; (void)n_in; (void)out_size; (void)ws_size;
  const float* hs    = (const float*)d_in[0];
  const float* amask = (const float*)d_in[1];
  const float* Wq = (const float*)d_in[2];
  const float* bq = (const float*)d_in[3];
  const float* Wk = (const float*)d_in[4];
  const float* bk = (const float*)d_in[5];
  const float* Wv = (const float*)d_in[6];
  const float* bv = (const float*)d_in[7];
  const float* Wo = (const float*)d_in[8];
  const float* bo = (const float*)d_in[9];
  float* out = (float*)d_out;
  char* ws = (char*)d_ws;
  short* Xb   = (short*)(ws);
  short* Wqkv = (short*)(ws + 12582912);
  short* Wob  = (short*)(ws + 16121856);
  short* qB   = (short*)(ws + 17301504);
  short* kB   = (short*)(ws + 29884416);
  short* vTB  = (short*)(ws + 42467328);
  short* ctx  = Xb;  // Xb dead after gemm_qkv

  cvt_x<<<dim3(6144), dim3(256), 0, stream>>>(hs, Xb, 8192 * 768 / 4);
  cvt_w<<<dim3(2304), dim3(256), 0, stream>>>(Wq, Wk, Wv, Wo, Wqkv, Wob);
  gemm_qkv<<<dim3(1152), dim3(256), 0, stream>>>(Xb, Wqkv, bq, bk, bv, qB, kB, vTB);
  attn<<<dim3(768), dim3(512), 0, stream>>>(qB, kB, vTB, amask, ctx);
  gemm_out<<<dim3(384), dim3(256), 0, stream>>>(ctx, Wob, bo, out);
}

// Round 17
// 126.279 us; speedup vs baseline: 1.6024x; 1.0403x over previous
//
#include <hip/hip_runtime.h>
#include <hip/hip_bf16.h>
#include <stdint.h>

#define NH 12
#define DH 64
#define SEQ 4096
#define DM 768
#define NEGV -1e9f
#define LOG2E 1.4426950408889634f
#define QSCALE 0.1803368801111601f  // 0.125 * log2(e)

using bf16x8 = __attribute__((ext_vector_type(8))) short;
using f32x4  = __attribute__((ext_vector_type(4))) float;

static __device__ __forceinline__ short f2bf(float f) {
  unsigned u = __builtin_bit_cast(unsigned, f);
  u += 0x7fffu + ((u >> 16) & 1u);
  return (short)(u >> 16);
}

static __device__ __forceinline__ unsigned pack2bf(float lo, float hi) {
  unsigned a = __builtin_bit_cast(unsigned, lo);
  a += 0x7fffu + ((a >> 16) & 1u);
  unsigned b = __builtin_bit_cast(unsigned, hi);
  b += 0x7fffu + ((b >> 16) & 1u);
  return (a >> 16) | (b & 0xffff0000u);
}

static __device__ __forceinline__ void gload16(const void* g, void* l) {
  __builtin_amdgcn_global_load_lds(
      (const __attribute__((address_space(1))) unsigned*)g,
      (__attribute__((address_space(3))) unsigned*)l, 16, 0, 0);
}

static __device__ __forceinline__ f32x4 mfma16(bf16x8 a, bf16x8 b, f32x4 c) {
  return __builtin_amdgcn_mfma_f32_16x16x32_bf16(a, b, c, 0, 0, 0);
}

#define SBAR() __builtin_amdgcn_sched_barrier(0)
#define WAIT8() asm volatile("s_waitcnt vmcnt(8)" ::: "memory")
#define WAIT0() asm volatile("s_waitcnt vmcnt(0)" ::: "memory")
#define HBAR() __builtin_amdgcn_s_barrier()

// ---------------- merged conversion kernel ----------------
// blocks [0,6144): hs -> Xb bf16; blocks [6144,8448): weights -> bf16
__global__ __launch_bounds__(256) void cvt_all(
    const float* __restrict__ X, short* __restrict__ Xb,
    const float* __restrict__ Wq, const float* __restrict__ Wk,
    const float* __restrict__ Wv, const float* __restrict__ Wo,
    short* __restrict__ Wqkv, short* __restrict__ Wob) {
  int i = blockIdx.x * 256 + threadIdx.x;
  const int nx = 8192 * 768 / 4;
  if (i < nx) {
    float4 v = ((const float4*)X)[i];
    short4 o; o.x = f2bf(v.x); o.y = f2bf(v.y); o.z = f2bf(v.z); o.w = f2bf(v.w);
    ((short4*)Xb)[i] = o;
    return;
  }
  i -= nx;
  const int n1 = 2304 * 768 / 4;
  if (i < n1) {
    int e = i * 4;
    int row = e / 768;
    const float* src;
    float sc = 1.0f;
    if (row < 768)       { src = Wq + e; sc = QSCALE; }
    else if (row < 1536) { src = Wk + e - 768 * 768; }
    else                 { src = Wv + e - 1536 * 768; }
    float4 v = *(const float4*)src;
    short4 o; o.x = f2bf(v.x * sc); o.y = f2bf(v.y * sc);
    o.z = f2bf(v.z * sc); o.w = f2bf(v.w * sc);
    ((short4*)Wqkv)[i] = o;
  } else {
    int j = i - n1;
    if (j >= 768 * 768 / 4) return;
    float4 v = ((const float4*)Wo)[j];
    short4 o; o.x = f2bf(v.x); o.y = f2bf(v.y); o.z = f2bf(v.z); o.w = f2bf(v.w);
    ((short4*)Wob)[j] = o;
  }
}

// ======= pipelined 128x128 GEMM core, BK=64, 2-buffer, counted vmcnt =======
// (R16 version — measured best)
#define GEMM_PIPELINE(SM, AG, BG, ACC, LANE, WR, WC)                           \
  {                                                                            \
    const int l15 = (LANE) & 15, gw = (LANE) >> 4;                             \
    const int s_ = (l15 >> 1) & 3;                                             \
    const int NT = 12; /* 768/64 */                                            \
    auto stage = [&](int t) {                                                  \
      short* ab = (SM) + ((t & 1) << 13);                                      \
      short* bb = (SM) + 16384 + ((t & 1) << 13);                              \
      int kt = t << 6;                                                         \
      gload16((AG) + kt, ab + ldst);                                           \
      gload16((AG) + kt + 32 * 768, ab + ldst + 2048);                         \
      gload16((AG) + kt + 64 * 768, ab + ldst + 4096);                         \
      gload16((AG) + kt + 96 * 768, ab + ldst + 6144);                         \
      gload16((BG) + kt, bb + ldst);                                           \
      gload16((BG) + kt + 32 * 768, bb + ldst + 2048);                         \
      gload16((BG) + kt + 64 * 768, bb + ldst + 4096);                         \
      gload16((BG) + kt + 96 * 768, bb + ldst + 6144);                         \
    };                                                                         \
    auto compute = [&](int t) {                                                \
      const short* ab = (SM) + ((t & 1) << 13);                                \
      const short* bb = (SM) + 16384 + ((t & 1) << 13);                        \
      _Pragma("unroll") for (int kk = 0; kk < 2; ++kk) {                       \
        const int fc = (((kk << 2) + (gw ^ s_)) << 3);                         \
        bf16x8 af[4], bf[4];                                                   \
        _Pragma("unroll") for (int mi = 0; mi < 4; ++mi)                       \
            af[mi] = *(const bf16x8*)(ab + ((WR) + mi * 16 + l15) * 64 + fc);  \
        _Pragma("unroll") for (int ni = 0; ni < 4; ++ni)                       \
            bf[ni] = *(const bf16x8*)(bb + ((WC) + ni * 16 + l15) * 64 + fc);  \
        __builtin_amdgcn_s_setprio(1);                                         \
        _Pragma("unroll") for (int mi = 0; mi < 4; ++mi)                       \
            _Pragma("unroll") for (int ni = 0; ni < 4; ++ni)                   \
                ACC[mi][ni] = mfma16(af[mi], bf[ni], ACC[mi][ni]);             \
        __builtin_amdgcn_s_setprio(0);                                         \
      }                                                                        \
    };                                                                         \
    stage(0); stage(1);                                                        \
    SBAR();                                                                    \
    _Pragma("unroll 1") for (int i = 0; i < NT; ++i) {                         \
      SBAR();                                                                  \
      if (i < NT - 1) { WAIT8(); } else { WAIT0(); }                           \
      HBAR(); SBAR();                                                          \
      compute(i);                                                              \
      SBAR(); HBAR();                                                          \
      if (i + 2 < NT) stage(i + 2);                                            \
    }                                                                          \
  }

// ---------------- QKV projection GEMM ----------------
__global__ __launch_bounds__(256) void gemm_qkv(
    const short* __restrict__ Xb, const short* __restrict__ Wqkv,
    const float* __restrict__ bq, const float* __restrict__ bk,
    const float* __restrict__ bv,
    short* __restrict__ qO, short* __restrict__ kO, short* __restrict__ vT) {
  __shared__ __align__(16) short sm[32768];
  const int tid = threadIdx.x, lane = tid & 63, wid = tid >> 6;
  const int xcd = blockIdx.x & 7, kk = blockIdx.x >> 3;  // kk in [0,144)
  const int m0 = (xcd * 8 + (kk & 7)) * 128;
  const int n0 = (kk >> 3) * 128;
  const int wr = (wid >> 1) * 64, wc = (wid & 1) * 64;
  const int srow = tid >> 3;                                    // 0..31
  const int scol = (((tid & 7) ^ ((tid >> 4) & 3)) << 3);       // swizzled granule
  const short* Ag = Xb + (m0 + srow) * 768 + scol;
  const short* Bg = Wqkv + (n0 + srow) * 768 + scol;
  const int ldst = tid * 8;

  const int src = n0 / 768;  // 0=q 1=k 2=v
  const int nloc = n0 % 768;
  float bias[4];
#pragma unroll
  for (int ni = 0; ni < 4; ++ni) {
    int c = nloc + wc + ni * 16 + (lane & 15);
    bias[ni] = (src == 0) ? bq[c] * QSCALE : (src == 1) ? bk[c] : bv[c];
  }
  WAIT0(); SBAR();

  f32x4 acc[4][4] = {};
  GEMM_PIPELINE(sm, Ag, Bg, acc, lane, wr, wc);

  const int bb = m0 >> 12;
  const int s0 = m0 & (SEQ - 1);
  __syncthreads();
  if (src < 2) {
#pragma unroll
    for (int mi = 0; mi < 4; ++mi)
#pragma unroll
      for (int ni = 0; ni < 4; ++ni) {
        int row = wr + mi * 16 + ((lane >> 4) << 2);
        int col = wc + ni * 16 + (lane & 15);
#pragma unroll
        for (int r = 0; r < 4; ++r)
          sm[(row + r) * 132 + col] = f2bf(acc[mi][ni][r] + bias[ni]);
      }
    __syncthreads();
    short* dst = (src == 0) ? qO : kO;
    for (int u = tid; u < 8192; u += 256) {
      int r = u >> 6, cp = (u & 63) << 1;
      unsigned val = *(const unsigned*)&sm[r * 132 + cp];
      int c = nloc + cp;
      int h = c >> 6, d = c & 63;
      *(unsigned*)&dst[(((bb * NH + h) * SEQ) + s0 + r) * DH + d] = val;
    }
  } else {
#pragma unroll
    for (int mi = 0; mi < 4; ++mi)
#pragma unroll
      for (int ni = 0; ni < 4; ++ni) {
        int row = wr + mi * 16 + ((lane >> 4) << 2);
        int col = wc + ni * 16 + (lane & 15);
        short4 pk;
        pk.x = f2bf(acc[mi][ni][0] + bias[ni]);
        pk.y = f2bf(acc[mi][ni][1] + bias[ni]);
        pk.z = f2bf(acc[mi][ni][2] + bias[ni]);
        pk.w = f2bf(acc[mi][ni][3] + bias[ni]);
        *(short4*)&sm[col * 132 + row] = pk;
      }
    __syncthreads();
    for (int u = tid; u < 8192; u += 256) {
      int cc = u >> 6, rp = (u & 63) << 1;
      unsigned val = *(const unsigned*)&sm[cc * 132 + rp];
      int c = nloc + cc;
      int h = c >> 6, d = c & 63;
      *(unsigned*)&vT[(((bb * NH + h) * DH) + d) * SEQ + s0 + rp] = val;
    }
  }
}

// ---------------- sliding-window attention (R6 + BiasL in LDS) --------------
__global__ __launch_bounds__(512, 4) void attn(
    const short* __restrict__ qI, const short* __restrict__ kI,
    const short* __restrict__ vT, const float* __restrict__ amask,
    short* __restrict__ ctx) {
  __shared__ __align__(16) short Ks[128 * 64];
  __shared__ __align__(16) short Vs[64 * 128];
  __shared__ __align__(16) short Ps[8][16 * 132];
  __shared__ __align__(16) float BiasL[768];
  const int tid = threadIdx.x, lane = tid & 63, wid = tid >> 6;
  const int vb_id = (blockIdx.x & 7) * 96 + (blockIdx.x >> 3);
  const int strip = vb_id & 31;
  const int hh = (vb_id >> 5) % 12;
  const int bb = vb_id / 384;
  const int s0 = strip * 128;
  const int n = s0 >> 8;
  const int i0 = s0 & 255;
  const int base = (n - 1) * 256;
  const int bh = bb * NH + hh;
  const int m = lane & 15, hq = lane >> 4;
  const int swz = m & 7;
  const int iw = i0 + (wid << 4);

  const short* qbase = qI + ((size_t)(bh * SEQ) + s0 + (wid << 4)) * DH;
  const bf16x8 aq0 = *(const bf16x8*)(qbase + m * DH + (hq << 3));
  const bf16x8 aq1 = *(const bf16x8*)(qbase + m * DH + 32 + (hq << 3));

  const int kb_s0 = m * 64 + ((hq ^ swz) << 3);
  const int kb_s1 = m * 64 + (((hq + 4) ^ swz) << 3);
  const int vk0 = m * 128 + ((hq ^ swz) << 3);
  const int vk1 = m * 128 + (((hq + 4) ^ swz) << 3);
  const int vk2 = m * 128 + (((hq + 8) ^ swz) << 3);
  const int vk3 = m * 128 + (((hq + 12) ^ swz) << 3);
  short* Pw = Ps[wid];
  const int pwr = m * 132;

  const int e0 = tid * 8, e1 = tid * 8 + 4096;
  const int kj0 = e0 >> 6, kj1 = e1 >> 6;
  const int ksrc0 = kj0 * DH + ((((e0 >> 3) & 7) ^ (kj0 & 7)) << 3);
  const int ksrc1 = kj1 * DH + ((((e1 >> 3) & 7) ^ (kj1 & 7)) << 3);
  const int vd0 = e0 >> 7, vd1 = e1 >> 7;
  const int vsrc0 = vd0 * SEQ + ((((e0 >> 3) & 15) ^ (vd0 & 7)) << 3);
  const int vsrc1 = vd1 * SEQ + ((((e1 >> 3) & 15) ^ (vd1 & 7)) << 3);

  const short* kg0 = kI + (size_t)bh * SEQ * DH;
  const short* vg0 = vT + (size_t)bh * DH * SEQ;

  // stage amask bias window once, pre-multiplied by -log2e.
  // Clamped entries correspond to skipped (OOB) chunks — never read.
  if (tid < 192) {
    int idx = base + tid * 4;
    idx = idx < 0 ? 0 : (idx > SEQ - 4 ? SEQ - 4 : idx);
    float4 bv = *(const float4*)(amask + bb * SEQ + idx);
    bv.x *= -LOG2E; bv.y *= -LOG2E; bv.z *= -LOG2E; bv.w *= -LOG2E;
    *(float4*)&BiasL[tid * 4] = bv;
  }

  f32x4 acc[4] = {};
  float mrow = -1e30f, lrow = 0.f;

#pragma unroll 1
  for (int c = 0; c < 6; ++c) {
    const int j0 = c << 7;
    const int kpos0 = base + j0;
    if (kpos0 < 0 || kpos0 >= SEQ) continue;
    if (j0 + 127 < i0 || j0 > i0 + 639) continue;

    __syncthreads();
    {
      const short* kb = kg0 + (size_t)kpos0 * DH;
      gload16(kb + ksrc0, (short*)Ks + e0);
      gload16(kb + ksrc1, (short*)Ks + e1);
      const short* vbp = vg0 + kpos0;
      gload16(vbp + vsrc0, (short*)Vs + e0);
      gload16(vbp + vsrc1, (short*)Vs + e1);
    }
    __syncthreads();

    f32x4 sc[8];
    __builtin_amdgcn_s_setprio(1);
#pragma unroll
    for (int jt = 0; jt < 8; ++jt) {
      bf16x8 k0 = *(const bf16x8*)(Ks + jt * 1024 + kb_s0);
      bf16x8 k1 = *(const bf16x8*)(Ks + jt * 1024 + kb_s1);
      f32x4 z = {};
      z = mfma16(k0, aq0, z);
      z = mfma16(k1, aq1, z);
      sc[jt] = z;
    }
    __builtin_amdgcn_s_setprio(0);

    const float* mp = BiasL + j0 + (hq << 2);
    float mn = mrow;
    const bool interior = (j0 >= iw + 15) && (j0 <= iw + 385);
    if (interior) {
#pragma unroll
      for (int jt = 0; jt < 8; ++jt) {
        float4 b4 = *(const float4*)(mp + jt * 16);
#pragma unroll
        for (int r = 0; r < 4; ++r) {
          float s = sc[jt][r] + (&b4.x)[r];
          sc[jt][r] = s;
          mn = fmaxf(mn, s);
        }
      }
    } else {
      const int iq = iw + m;
#pragma unroll
      for (int jt = 0; jt < 8; ++jt) {
        float4 b4 = *(const float4*)(mp + jt * 16);
        const int jb = j0 + jt * 16 + (hq << 2);
#pragma unroll
        for (int r = 0; r < 4; ++r) {
          int j = jb + r;
          float s = sc[jt][r] + (&b4.x)[r];
          s = (j >= iq && j <= iq + 512) ? s : NEGV;
          sc[jt][r] = s;
          mn = fmaxf(mn, s);
        }
      }
    }
    mn = fmaxf(mn, __shfl_xor(mn, 16));
    mn = fmaxf(mn, __shfl_xor(mn, 32));

    float l0 = 0.f;
#pragma unroll
    for (int jt = 0; jt < 8; ++jt) {
      float p0 = exp2f(sc[jt][0] - mn);
      float p1 = exp2f(sc[jt][1] - mn);
      float p2 = exp2f(sc[jt][2] - mn);
      float p3 = exp2f(sc[jt][3] - mn);
      l0 += (p0 + p1) + (p2 + p3);
      uint2 u;
      u.x = pack2bf(p0, p1);
      u.y = pack2bf(p2, p3);
      *(uint2*)(Pw + pwr + jt * 16 + (hq << 2)) = u;
    }
    l0 += __shfl_xor(l0, 16);
    l0 += __shfl_xor(l0, 32);
    const float scl = exp2f(mrow - mn);
    lrow = lrow * scl + l0;
    mrow = mn;
    const float s0r = __shfl(scl, (hq << 2) + 0);
    const float s1r = __shfl(scl, (hq << 2) + 1);
    const float s2r = __shfl(scl, (hq << 2) + 2);
    const float s3r = __shfl(scl, (hq << 2) + 3);
#pragma unroll
    for (int nt = 0; nt < 4; ++nt) {
      acc[nt][0] *= s0r; acc[nt][1] *= s1r;
      acc[nt][2] *= s2r; acc[nt][3] *= s3r;
    }

    asm volatile("s_waitcnt lgkmcnt(0)" ::: "memory");
    __builtin_amdgcn_sched_barrier(0);

    __builtin_amdgcn_s_setprio(1);
#pragma unroll
    for (int ks = 0; ks < 4; ++ks) {
      bf16x8 pa = *(const bf16x8*)(Pw + pwr + ks * 32 + (hq << 3));
      const int vkk = (ks == 0) ? vk0 : (ks == 1) ? vk1 : (ks == 2) ? vk2 : vk3;
#pragma unroll
      for (int nt = 0; nt < 4; ++nt) {
        bf16x8 vv = *(const bf16x8*)(Vs + nt * 2048 + vkk);
        acc[nt] = mfma16(pa, vv, acc[nt]);
      }
    }
    __builtin_amdgcn_s_setprio(0);
  }

  const float inv = 1.0f / lrow;
  const float i0r = __shfl(inv, (hq << 2) + 0);
  const float i1r = __shfl(inv, (hq << 2) + 1);
  const float i2r = __shfl(inv, (hq << 2) + 2);
  const float i3r = __shfl(inv, (hq << 2) + 3);
#pragma unroll
  for (int nt = 0; nt < 4; ++nt) {
    Pw[((hq << 2) + 0) * 72 + nt * 16 + m] = f2bf(acc[nt][0] * i0r);
    Pw[((hq << 2) + 1) * 72 + nt * 16 + m] = f2bf(acc[nt][1] * i1r);
    Pw[((hq << 2) + 2) * 72 + nt * 16 + m] = f2bf(acc[nt][2] * i2r);
    Pw[((hq << 2) + 3) * 72 + nt * 16 + m] = f2bf(acc[nt][3] * i3r);
  }
  asm volatile("s_waitcnt lgkmcnt(0)" ::: "memory");
  __builtin_amdgcn_sched_barrier(0);
#pragma unroll
  for (int it = 0; it < 2; ++it) {
    int row = it * 8 + (lane >> 3);
    bf16x8 val = *(const bf16x8*)(Pw + row * 72 + ((lane & 7) << 3));
    *(bf16x8*)(ctx + ((size_t)(bb * SEQ) + s0 + (wid << 4) + row) * DM +
               hh * DH + ((lane & 7) << 3)) = val;
  }
}

// ---------------- output projection GEMM (BK=64 pipelined) ----------------
__global__ __launch_bounds__(256) void gemm_out(
    const short* __restrict__ Cb, const short* __restrict__ Wob,
    const float* __restrict__ bo, float* __restrict__ out) {
  __shared__ __align__(16) short sm[32768];
  const int tid = threadIdx.x, lane = tid & 63, wid = tid >> 6;
  const int xcd = blockIdx.x & 7, kk = blockIdx.x >> 3;  // kk in [0,48)
  const int m0 = (xcd * 8 + (kk & 7)) * 128;
  const int n0 = (kk >> 3) * 128;
  const int wr = (wid >> 1) * 64, wc = (wid & 1) * 64;
  const int srow = tid >> 3;
  const int scol = (((tid & 7) ^ ((tid >> 4) & 3)) << 3);
  const short* Ag = Cb + (m0 + srow) * 768 + scol;
  const short* Bg = Wob + (n0 + srow) * 768 + scol;
  const int ldst = tid * 8;

  float bias[4];
#pragma unroll
  for (int ni = 0; ni < 4; ++ni)
    bias[ni] = bo[n0 + wc + ni * 16 + (lane & 15)];
  WAIT0(); SBAR();

  f32x4 acc[4][4] = {};
  GEMM_PIPELINE(sm, Ag, Bg, acc, lane, wr, wc);

#pragma unroll
  for (int mi = 0; mi < 4; ++mi)
#pragma unroll
    for (int ni = 0; ni < 4; ++ni) {
      int row = m0 + wr + mi * 16 + ((lane >> 4) << 2);
      int col = n0 + wc + ni * 16 + (lane & 15);
#pragma unroll
      for (int r = 0; r < 4; ++r)
        out[(row + r) * DM + col] = acc[mi][ni][r] + bias[ni];
    }
}

// ---------------- launcher ----------------
extern "C" void kernel_launch(void* const* d_in, const int* in_sizes, int n_in,
                              void* d_out, int out_size, void* d_ws, size_t ws_size,
                              hipStream_t stream) {
  (void)in_sizes; (void)n_in; (void)out_size; (void)ws_size;
  const float* hs    = (const float*)d_in[0];
  const float* amask = (const float*)d_in[1];
  const float* Wq = (const float*)d_in[2];
  const float* bq = (const float*)d_in[3];
  const float* Wk = (const float*)d_in[4];
  const float* bk = (const float*)d_in[5];
  const float* Wv = (const float*)d_in[6];
  const float* bv = (const float*)d_in[7];
  const float* Wo = (const float*)d_in[8];
  const float* bo = (const float*)d_in[9];
  float* out = (float*)d_out;
  char* ws = (char*)d_ws;
  short* Xb   = (short*)(ws);
  short* Wqkv = (short*)(ws + 12582912);
  short* Wob  = (short*)(ws + 16121856);
  short* qB   = (short*)(ws + 17301504);
  short* kB   = (short*)(ws + 29884416);
  short* vTB  = (short*)(ws + 42467328);
  short* ctx  = Xb;  // Xb dead after gemm_qkv

  cvt_all<<<dim3(8448), dim3(256), 0, stream>>>(hs, Xb, Wq, Wk, Wv, Wo, Wqkv, Wob);
  gemm_qkv<<<dim3(1152), dim3(256), 0, stream>>>(Xb, Wqkv, bq, bk, bv, qB, kB, vTB);
  attn<<<dim3(768), dim3(512), 0, stream>>>(qB, kB, vTB, amask, ctx);
  gemm_out<<<dim3(384), dim3(256), 0, stream>>>(ctx, Wob, bo, out);
}

// Round 18
// 123.786 us; speedup vs baseline: 1.6346x; 1.0201x over previous
//
#include <hip/hip_runtime.h>
#include <hip/hip_bf16.h>
#include <stdint.h>

#define NH 12
#define DH 64
#define SEQ 4096
#define DM 768
#define NEGV -1e9f
#define LOG2E 1.4426950408889634f
#define QSCALE 0.1803368801111601f  // 0.125 * log2(e)

using bf16x8 = __attribute__((ext_vector_type(8))) short;
using f32x4  = __attribute__((ext_vector_type(4))) float;

static __device__ __forceinline__ short f2bf(float f) {
  unsigned u = __builtin_bit_cast(unsigned, f);
  u += 0x7fffu + ((u >> 16) & 1u);
  return (short)(u >> 16);
}

// round-half-up bf16 pair pack via v_perm_b32 (3 VALU vs 6 for RNE)
static __device__ __forceinline__ unsigned pack2bf_rnd(float lo, float hi) {
  unsigned a = __builtin_bit_cast(unsigned, lo) + 0x8000u;
  unsigned b = __builtin_bit_cast(unsigned, hi) + 0x8000u;
  return __builtin_amdgcn_perm(b, a, 0x07060302u);
}

static __device__ __forceinline__ void gload16(const void* g, void* l) {
  __builtin_amdgcn_global_load_lds(
      (const __attribute__((address_space(1))) unsigned*)g,
      (__attribute__((address_space(3))) unsigned*)l, 16, 0, 0);
}

static __device__ __forceinline__ f32x4 mfma16(bf16x8 a, bf16x8 b, f32x4 c) {
  return __builtin_amdgcn_mfma_f32_16x16x32_bf16(a, b, c, 0, 0, 0);
}

#define SBAR() __builtin_amdgcn_sched_barrier(0)
#define WAIT8() asm volatile("s_waitcnt vmcnt(8)" ::: "memory")
#define WAIT0() asm volatile("s_waitcnt vmcnt(0)" ::: "memory")
#define HBAR() __builtin_amdgcn_s_barrier()

// ---------------- merged conversion kernel ----------------
__global__ __launch_bounds__(256) void cvt_all(
    const float* __restrict__ X, short* __restrict__ Xb,
    const float* __restrict__ Wq, const float* __restrict__ Wk,
    const float* __restrict__ Wv, const float* __restrict__ Wo,
    short* __restrict__ Wqkv, short* __restrict__ Wob) {
  int i = blockIdx.x * 256 + threadIdx.x;
  const int nx = 8192 * 768 / 4;
  if (i < nx) {
    float4 v = ((const float4*)X)[i];
    short4 o; o.x = f2bf(v.x); o.y = f2bf(v.y); o.z = f2bf(v.z); o.w = f2bf(v.w);
    ((short4*)Xb)[i] = o;
    return;
  }
  i -= nx;
  const int n1 = 2304 * 768 / 4;
  if (i < n1) {
    int e = i * 4;
    int row = e / 768;
    const float* src;
    float sc = 1.0f;
    if (row < 768)       { src = Wq + e; sc = QSCALE; }
    else if (row < 1536) { src = Wk + e - 768 * 768; }
    else                 { src = Wv + e - 1536 * 768; }
    float4 v = *(const float4*)src;
    short4 o; o.x = f2bf(v.x * sc); o.y = f2bf(v.y * sc);
    o.z = f2bf(v.z * sc); o.w = f2bf(v.w * sc);
    ((short4*)Wqkv)[i] = o;
  } else {
    int j = i - n1;
    if (j >= 768 * 768 / 4) return;
    float4 v = ((const float4*)Wo)[j];
    short4 o; o.x = f2bf(v.x); o.y = f2bf(v.y); o.z = f2bf(v.z); o.w = f2bf(v.w);
    ((short4*)Wob)[j] = o;
  }
}

// ======= pipelined 128x128 GEMM core, BK=64, 2-buffer, counted vmcnt =======
#define GEMM_PIPELINE(SM, AG, BG, ACC, LANE, WR, WC)                           \
  {                                                                            \
    const int l15 = (LANE) & 15, gw = (LANE) >> 4;                             \
    const int s_ = (l15 >> 1) & 3;                                             \
    const int NT = 12; /* 768/64 */                                            \
    auto stage = [&](int t) {                                                  \
      short* ab = (SM) + ((t & 1) << 13);                                      \
      short* bb = (SM) + 16384 + ((t & 1) << 13);                              \
      int kt = t << 6;                                                         \
      gload16((AG) + kt, ab + ldst);                                           \
      gload16((AG) + kt + 32 * 768, ab + ldst + 2048);                         \
      gload16((AG) + kt + 64 * 768, ab + ldst + 4096);                         \
      gload16((AG) + kt + 96 * 768, ab + ldst + 6144);                         \
      gload16((BG) + kt, bb + ldst);                                           \
      gload16((BG) + kt + 32 * 768, bb + ldst + 2048);                         \
      gload16((BG) + kt + 64 * 768, bb + ldst + 4096);                         \
      gload16((BG) + kt + 96 * 768, bb + ldst + 6144);                         \
    };                                                                         \
    auto compute = [&](int t) {                                                \
      const short* ab = (SM) + ((t & 1) << 13);                                \
      const short* bb = (SM) + 16384 + ((t & 1) << 13);                        \
      _Pragma("unroll") for (int kk = 0; kk < 2; ++kk) {                       \
        const int fc = (((kk << 2) + (gw ^ s_)) << 3);                         \
        bf16x8 af[4], bf[4];                                                   \
        _Pragma("unroll") for (int mi = 0; mi < 4; ++mi)                       \
            af[mi] = *(const bf16x8*)(ab + ((WR) + mi * 16 + l15) * 64 + fc);  \
        _Pragma("unroll") for (int ni = 0; ni < 4; ++ni)                       \
            bf[ni] = *(const bf16x8*)(bb + ((WC) + ni * 16 + l15) * 64 + fc);  \
        __builtin_amdgcn_s_setprio(1);                                         \
        _Pragma("unroll") for (int mi = 0; mi < 4; ++mi)                       \
            _Pragma("unroll") for (int ni = 0; ni < 4; ++ni)                   \
                ACC[mi][ni] = mfma16(af[mi], bf[ni], ACC[mi][ni]);             \
        __builtin_amdgcn_s_setprio(0);                                         \
      }                                                                        \
    };                                                                         \
    stage(0); stage(1);                                                        \
    SBAR();                                                                    \
    _Pragma("unroll 1") for (int i = 0; i < NT; ++i) {                         \
      SBAR();                                                                  \
      if (i < NT - 1) { WAIT8(); } else { WAIT0(); }                           \
      HBAR(); SBAR();                                                          \
      compute(i);                                                              \
      SBAR(); HBAR();                                                          \
      if (i + 2 < NT) stage(i + 2);                                            \
    }                                                                          \
  }

// ---------------- QKV projection GEMM ----------------
__global__ __launch_bounds__(256) void gemm_qkv(
    const short* __restrict__ Xb, const short* __restrict__ Wqkv,
    const float* __restrict__ bq, const float* __restrict__ bk,
    const float* __restrict__ bv,
    short* __restrict__ qO, short* __restrict__ kO, short* __restrict__ vT) {
  __shared__ __align__(16) short sm[32768];
  const int tid = threadIdx.x, lane = tid & 63, wid = tid >> 6;
  const int xcd = blockIdx.x & 7, kk = blockIdx.x >> 3;  // kk in [0,144)
  const int m0 = (xcd * 8 + (kk & 7)) * 128;
  const int n0 = (kk >> 3) * 128;
  const int wr = (wid >> 1) * 64, wc = (wid & 1) * 64;
  const int srow = tid >> 3;
  const int scol = (((tid & 7) ^ ((tid >> 4) & 3)) << 3);
  const short* Ag = Xb + (m0 + srow) * 768 + scol;
  const short* Bg = Wqkv + (n0 + srow) * 768 + scol;
  const int ldst = tid * 8;

  const int src = n0 / 768;  // 0=q 1=k 2=v
  const int nloc = n0 % 768;
  float bias[4];
#pragma unroll
  for (int ni = 0; ni < 4; ++ni) {
    int c = nloc + wc + ni * 16 + (lane & 15);
    bias[ni] = (src == 0) ? bq[c] * QSCALE : (src == 1) ? bk[c] : bv[c];
  }
  WAIT0(); SBAR();

  f32x4 acc[4][4] = {};
  GEMM_PIPELINE(sm, Ag, Bg, acc, lane, wr, wc);

  const int bb = m0 >> 12;
  const int s0 = m0 & (SEQ - 1);
  __syncthreads();
  if (src < 2) {
#pragma unroll
    for (int mi = 0; mi < 4; ++mi)
#pragma unroll
      for (int ni = 0; ni < 4; ++ni) {
        int row = wr + mi * 16 + ((lane >> 4) << 2);
        int col = wc + ni * 16 + (lane & 15);
#pragma unroll
        for (int r = 0; r < 4; ++r)
          sm[(row + r) * 132 + col] = f2bf(acc[mi][ni][r] + bias[ni]);
      }
    __syncthreads();
    short* dst = (src == 0) ? qO : kO;
    for (int u = tid; u < 8192; u += 256) {
      int r = u >> 6, cp = (u & 63) << 1;
      unsigned val = *(const unsigned*)&sm[r * 132 + cp];
      int c = nloc + cp;
      int h = c >> 6, d = c & 63;
      *(unsigned*)&dst[(((bb * NH + h) * SEQ) + s0 + r) * DH + d] = val;
    }
  } else {
#pragma unroll
    for (int mi = 0; mi < 4; ++mi)
#pragma unroll
      for (int ni = 0; ni < 4; ++ni) {
        int row = wr + mi * 16 + ((lane >> 4) << 2);
        int col = wc + ni * 16 + (lane & 15);
        short4 pk;
        pk.x = f2bf(acc[mi][ni][0] + bias[ni]);
        pk.y = f2bf(acc[mi][ni][1] + bias[ni]);
        pk.z = f2bf(acc[mi][ni][2] + bias[ni]);
        pk.w = f2bf(acc[mi][ni][3] + bias[ni]);
        *(short4*)&sm[col * 132 + row] = pk;
      }
    __syncthreads();
    for (int u = tid; u < 8192; u += 256) {
      int cc = u >> 6, rp = (u & 63) << 1;
      unsigned val = *(const unsigned*)&sm[cc * 132 + rp];
      int c = nloc + cc;
      int h = c >> 6, d = c & 63;
      *(unsigned*)&vT[(((bb * NH + h) * DH) + d) * SEQ + s0 + rp] = val;
    }
  }
}

// ---------------- sliding-window attention ----------------
// R17 structure + defer-max (THR=8), deferred l-reduce, perm P-pack.
__global__ __launch_bounds__(512, 4) void attn(
    const short* __restrict__ qI, const short* __restrict__ kI,
    const short* __restrict__ vT, const float* __restrict__ amask,
    short* __restrict__ ctx) {
  __shared__ __align__(16) short Ks[128 * 64];
  __shared__ __align__(16) short Vs[64 * 128];
  __shared__ __align__(16) short Ps[8][16 * 132];
  __shared__ __align__(16) float BiasL[768];
  const int tid = threadIdx.x, lane = tid & 63, wid = tid >> 6;
  const int vb_id = (blockIdx.x & 7) * 96 + (blockIdx.x >> 3);
  const int strip = vb_id & 31;
  const int hh = (vb_id >> 5) % 12;
  const int bb = vb_id / 384;
  const int s0 = strip * 128;
  const int n = s0 >> 8;
  const int i0 = s0 & 255;
  const int base = (n - 1) * 256;
  const int bh = bb * NH + hh;
  const int m = lane & 15, hq = lane >> 4;
  const int swz = m & 7;
  const int iw = i0 + (wid << 4);

  const short* qbase = qI + ((size_t)(bh * SEQ) + s0 + (wid << 4)) * DH;
  const bf16x8 aq0 = *(const bf16x8*)(qbase + m * DH + (hq << 3));
  const bf16x8 aq1 = *(const bf16x8*)(qbase + m * DH + 32 + (hq << 3));

  const int kb_s0 = m * 64 + ((hq ^ swz) << 3);
  const int kb_s1 = m * 64 + (((hq + 4) ^ swz) << 3);
  const int vk0 = m * 128 + ((hq ^ swz) << 3);
  const int vk1 = m * 128 + (((hq + 4) ^ swz) << 3);
  const int vk2 = m * 128 + (((hq + 8) ^ swz) << 3);
  const int vk3 = m * 128 + (((hq + 12) ^ swz) << 3);
  short* Pw = Ps[wid];
  const int pwr = m * 132;

  const int e0 = tid * 8, e1 = tid * 8 + 4096;
  const int kj0 = e0 >> 6, kj1 = e1 >> 6;
  const int ksrc0 = kj0 * DH + ((((e0 >> 3) & 7) ^ (kj0 & 7)) << 3);
  const int ksrc1 = kj1 * DH + ((((e1 >> 3) & 7) ^ (kj1 & 7)) << 3);
  const int vd0 = e0 >> 7, vd1 = e1 >> 7;
  const int vsrc0 = vd0 * SEQ + ((((e0 >> 3) & 15) ^ (vd0 & 7)) << 3);
  const int vsrc1 = vd1 * SEQ + ((((e1 >> 3) & 15) ^ (vd1 & 7)) << 3);

  const short* kg0 = kI + (size_t)bh * SEQ * DH;
  const short* vg0 = vT + (size_t)bh * DH * SEQ;

  // stage amask bias window once, pre-multiplied by -log2e
  if (tid < 192) {
    int idx = base + tid * 4;
    idx = idx < 0 ? 0 : (idx > SEQ - 4 ? SEQ - 4 : idx);
    float4 bv = *(const float4*)(amask + bb * SEQ + idx);
    bv.x *= -LOG2E; bv.y *= -LOG2E; bv.z *= -LOG2E; bv.w *= -LOG2E;
    *(float4*)&BiasL[tid * 4] = bv;
  }

  f32x4 acc[4] = {};
  float mrow = -1e30f, lrow = 0.f;  // lrow = per-lane partial

#pragma unroll 1
  for (int c = 0; c < 6; ++c) {
    const int j0 = c << 7;
    const int kpos0 = base + j0;
    if (kpos0 < 0 || kpos0 >= SEQ) continue;
    if (j0 + 127 < i0 || j0 > i0 + 639) continue;

    __syncthreads();
    {
      const short* kb = kg0 + (size_t)kpos0 * DH;
      gload16(kb + ksrc0, (short*)Ks + e0);
      gload16(kb + ksrc1, (short*)Ks + e1);
      const short* vbp = vg0 + kpos0;
      gload16(vbp + vsrc0, (short*)Vs + e0);
      gload16(vbp + vsrc1, (short*)Vs + e1);
    }
    __syncthreads();

    f32x4 sc[8];
    __builtin_amdgcn_s_setprio(1);
#pragma unroll
    for (int jt = 0; jt < 8; ++jt) {
      bf16x8 k0 = *(const bf16x8*)(Ks + jt * 1024 + kb_s0);
      bf16x8 k1 = *(const bf16x8*)(Ks + jt * 1024 + kb_s1);
      f32x4 z = {};
      z = mfma16(k0, aq0, z);
      z = mfma16(k1, aq1, z);
      sc[jt] = z;
    }
    __builtin_amdgcn_s_setprio(0);

    // bias (LDS) + (edge-only) band mask + per-lane max
    const float* mp = BiasL + j0 + (hq << 2);
    float mn_l = -3e38f;
    const bool interior = (j0 >= iw + 15) && (j0 <= iw + 385);
    if (interior) {
#pragma unroll
      for (int jt = 0; jt < 8; ++jt) {
        float4 b4 = *(const float4*)(mp + jt * 16);
#pragma unroll
        for (int r = 0; r < 4; ++r) {
          float s = sc[jt][r] + (&b4.x)[r];
          sc[jt][r] = s;
          mn_l = fmaxf(mn_l, s);
        }
      }
    } else {
      const int iq = iw + m;
#pragma unroll
      for (int jt = 0; jt < 8; ++jt) {
        float4 b4 = *(const float4*)(mp + jt * 16);
        const int jb = j0 + jt * 16 + (hq << 2);
#pragma unroll
        for (int r = 0; r < 4; ++r) {
          int j = jb + r;
          float s = sc[jt][r] + (&b4.x)[r];
          s = (j >= iq && j <= iq + 512) ? s : NEGV;
          sc[jt][r] = s;
          mn_l = fmaxf(mn_l, s);
        }
      }
    }

    // T13 defer-max: full reduce + rescale only when bound exceeded
    if (__any(mn_l > mrow + 8.0f)) {
      float mn = fmaxf(mrow, mn_l);
      mn = fmaxf(mn, __shfl_xor(mn, 16));
      mn = fmaxf(mn, __shfl_xor(mn, 32));
      const float scl = exp2f(mrow - mn);
      mrow = mn;
      lrow *= scl;  // own-lane q=m partial
      const float s0r = __shfl(scl, (hq << 2) + 0);
      const float s1r = __shfl(scl, (hq << 2) + 1);
      const float s2r = __shfl(scl, (hq << 2) + 2);
      const float s3r = __shfl(scl, (hq << 2) + 3);
#pragma unroll
      for (int nt = 0; nt < 4; ++nt) {
        acc[nt][0] *= s0r; acc[nt][1] *= s1r;
        acc[nt][2] *= s2r; acc[nt][3] *= s3r;
      }
    }

    float l0 = 0.f;
#pragma unroll
    for (int jt = 0; jt < 8; ++jt) {
      float p0 = exp2f(sc[jt][0] - mrow);
      float p1 = exp2f(sc[jt][1] - mrow);
      float p2 = exp2f(sc[jt][2] - mrow);
      float p3 = exp2f(sc[jt][3] - mrow);
      l0 += (p0 + p1) + (p2 + p3);
      uint2 u;
      u.x = pack2bf_rnd(p0, p1);
      u.y = pack2bf_rnd(p2, p3);
      *(uint2*)(Pw + pwr + jt * 16 + (hq << 2)) = u;
    }
    lrow += l0;

    asm volatile("s_waitcnt lgkmcnt(0)" ::: "memory");
    __builtin_amdgcn_sched_barrier(0);

    __builtin_amdgcn_s_setprio(1);
#pragma unroll
    for (int ks = 0; ks < 4; ++ks) {
      bf16x8 pa = *(const bf16x8*)(Pw + pwr + ks * 32 + (hq << 3));
      const int vkk = (ks == 0) ? vk0 : (ks == 1) ? vk1 : (ks == 2) ? vk2 : vk3;
#pragma unroll
      for (int nt = 0; nt < 4; ++nt) {
        bf16x8 vv = *(const bf16x8*)(Vs + nt * 2048 + vkk);
        acc[nt] = mfma16(pa, vv, acc[nt]);
      }
    }
    __builtin_amdgcn_s_setprio(0);
  }

  // epilogue: deferred l-reduce, normalize, restage, coalesced stores
  lrow += __shfl_xor(lrow, 16);
  lrow += __shfl_xor(lrow, 32);
  const float inv = 1.0f / lrow;
  const float i0r = __shfl(inv, (hq << 2) + 0);
  const float i1r = __shfl(inv, (hq << 2) + 1);
  const float i2r = __shfl(inv, (hq << 2) + 2);
  const float i3r = __shfl(inv, (hq << 2) + 3);
#pragma unroll
  for (int nt = 0; nt < 4; ++nt) {
    Pw[((hq << 2) + 0) * 72 + nt * 16 + m] = f2bf(acc[nt][0] * i0r);
    Pw[((hq << 2) + 1) * 72 + nt * 16 + m] = f2bf(acc[nt][1] * i1r);
    Pw[((hq << 2) + 2) * 72 + nt * 16 + m] = f2bf(acc[nt][2] * i2r);
    Pw[((hq << 2) + 3) * 72 + nt * 16 + m] = f2bf(acc[nt][3] * i3r);
  }
  asm volatile("s_waitcnt lgkmcnt(0)" ::: "memory");
  __builtin_amdgcn_sched_barrier(0);
#pragma unroll
  for (int it = 0; it < 2; ++it) {
    int row = it * 8 + (lane >> 3);
    bf16x8 val = *(const bf16x8*)(Pw + row * 72 + ((lane & 7) << 3));
    *(bf16x8*)(ctx + ((size_t)(bb * SEQ) + s0 + (wid << 4) + row) * DM +
               hh * DH + ((lane & 7) << 3)) = val;
  }
}

// ---------------- output projection GEMM (BK=64 pipelined) ----------------
__global__ __launch_bounds__(256) void gemm_out(
    const short* __restrict__ Cb, const short* __restrict__ Wob,
    const float* __restrict__ bo, float* __restrict__ out) {
  __shared__ __align__(16) short sm[32768];
  const int tid = threadIdx.x, lane = tid & 63, wid = tid >> 6;
  const int xcd = blockIdx.x & 7, kk = blockIdx.x >> 3;  // kk in [0,48)
  const int m0 = (xcd * 8 + (kk & 7)) * 128;
  const int n0 = (kk >> 3) * 128;
  const int wr = (wid >> 1) * 64, wc = (wid & 1) * 64;
  const int srow = tid >> 3;
  const int scol = (((tid & 7) ^ ((tid >> 4) & 3)) << 3);
  const short* Ag = Cb + (m0 + srow) * 768 + scol;
  const short* Bg = Wob + (n0 + srow) * 768 + scol;
  const int ldst = tid * 8;

  float bias[4];
#pragma unroll
  for (int ni = 0; ni < 4; ++ni)
    bias[ni] = bo[n0 + wc + ni * 16 + (lane & 15)];
  WAIT0(); SBAR();

  f32x4 acc[4][4] = {};
  GEMM_PIPELINE(sm, Ag, Bg, acc, lane, wr, wc);

#pragma unroll
  for (int mi = 0; mi < 4; ++mi)
#pragma unroll
    for (int ni = 0; ni < 4; ++ni) {
      int row = m0 + wr + mi * 16 + ((lane >> 4) << 2);
      int col = n0 + wc + ni * 16 + (lane & 15);
#pragma unroll
      for (int r = 0; r < 4; ++r)
        out[(row + r) * DM + col] = acc[mi][ni][r] + bias[ni];
    }
}

// ---------------- launcher ----------------
extern "C" void kernel_launch(void* const* d_in, const int* in_sizes, int n_in,
                              void* d_out, int out_size, void* d_ws, size_t ws_size,
                              hipStream_t stream) {
  (void)in_sizes; (void)n_in; (void)out_size; (void)ws_size;
  const float* hs    = (const float*)d_in[0];
  const float* amask = (const float*)d_in[1];
  const float* Wq = (const float*)d_in[2];
  const float* bq = (const float*)d_in[3];
  const float* Wk = (const float*)d_in[4];
  const float* bk = (const float*)d_in[5];
  const float* Wv = (const float*)d_in[6];
  const float* bv = (const float*)d_in[7];
  const float* Wo = (const float*)d_in[8];
  const float* bo = (const float*)d_in[9];
  float* out = (float*)d_out;
  char* ws = (char*)d_ws;
  short* Xb   = (short*)(ws);
  short* Wqkv = (short*)(ws + 12582912);
  short* Wob  = (short*)(ws + 16121856);
  short* qB   = (short*)(ws + 17301504);
  short* kB   = (short*)(ws + 29884416);
  short* vTB  = (short*)(ws + 42467328);
  short* ctx  = Xb;  // Xb dead after gemm_qkv

  cvt_all<<<dim3(8448), dim3(256), 0, stream>>>(hs, Xb, Wq, Wk, Wv, Wo, Wqkv, Wob);
  gemm_qkv<<<dim3(1152), dim3(256), 0, stream>>>(Xb, Wqkv, bq, bk, bv, qB, kB, vTB);
  attn<<<dim3(768), dim3(512), 0, stream>>>(qB, kB, vTB, amask, ctx);
  gemm_out<<<dim3(384), dim3(256), 0, stream>>>(ctx, Wob, bo, out);
}